// Round 1
// baseline (5278.176 us; speedup 1.0000x reference)
//
#include <hip/hip_runtime.h>
#include <hip/hip_bf16.h>

// Problem constants
constexpr int CB = 16, CS = 512, CE = 256, CH = 8, CDK = 32;
constexpr int CNDYN = 6;
constexpr int CT = CB * CS;          // 8192 tokens
constexpr float SCALE = 0.17677669529663687f; // 1/sqrt(32)

// ---------------------------------------------------------------- embeddings
__global__ __launch_bounds__(256) void embed_kernel(
    const int* __restrict__ skills, const int* __restrict__ responses,
    const int* __restrict__ questions,
    const float* __restrict__ q_embed, const float* __restrict__ qa_embed,
    const float* __restrict__ q_embed_diff, const float* __restrict__ qa_embed_diff,
    const float* __restrict__ difficult,
    float* __restrict__ q_emb, float* __restrict__ qa_emb)
{
    int t = blockIdx.x;
    int e = threadIdx.x;
    int sk = skills[t];
    int r  = responses[t];
    r = (r > -1) ? r : 0;            // masked_r
    float pid = difficult[questions[t]];
    float qe  = q_embed[(size_t)sk * CE + e];
    float qd  = q_embed_diff[(size_t)sk * CE + e];
    float qv  = qe + pid * qd;
    float qae = qe + qa_embed[(size_t)r * CE + e];
    float qad = qa_embed_diff[((size_t)sk + 1000 * r) * CE + e];
    float qav = qae + pid * (qad + qd);
    q_emb[(size_t)t * CE + e]  = qv;
    qa_emb[(size_t)t * CE + e] = qav;
}

// ---------------------------------------------------------------- generic GEMM
// C[M,N] = A[M,K] @ W[K,N] + bias, optional relu.  M%64==0, N%64==0, K%16==0.
#define TBM 64
#define TBN 64
#define TBK 16
__global__ __launch_bounds__(256) void gemm_bias(
    const float* __restrict__ A, const float* __restrict__ W,
    const float* __restrict__ bias, float* __restrict__ C,
    int M, int N, int K, int relu)
{
    __shared__ float As[TBK][TBM + 1];
    __shared__ float Ws[TBK][TBN];
    int tid = threadIdx.x;
    int bm = blockIdx.y * TBM;
    int bn = blockIdx.x * TBN;
    int tx = tid & 15, ty = tid >> 4;
    float acc[4][4] = {};
    for (int k0 = 0; k0 < K; k0 += TBK) {
        {   // A tile: 64x16
            int idx = tid * 4;
            int m = idx >> 4, k = idx & 15;
            float4 v = *reinterpret_cast<const float4*>(&A[(size_t)(bm + m) * K + k0 + k]);
            As[k + 0][m] = v.x; As[k + 1][m] = v.y; As[k + 2][m] = v.z; As[k + 3][m] = v.w;
        }
        {   // W tile: 16x64
            int idx = tid * 4;
            int k = idx >> 6, n = idx & 63;
            float4 v = *reinterpret_cast<const float4*>(&W[(size_t)(k0 + k) * N + bn + n]);
            *reinterpret_cast<float4*>(&Ws[k][n]) = v;
        }
        __syncthreads();
#pragma unroll
        for (int k = 0; k < TBK; ++k) {
            float a[4], w[4];
#pragma unroll
            for (int i = 0; i < 4; ++i) a[i] = As[k][ty * 4 + i];
#pragma unroll
            for (int j = 0; j < 4; ++j) w[j] = Ws[k][tx * 4 + j];
#pragma unroll
            for (int i = 0; i < 4; ++i)
#pragma unroll
                for (int j = 0; j < 4; ++j) acc[i][j] += a[i] * w[j];
        }
        __syncthreads();
    }
#pragma unroll
    for (int i = 0; i < 4; ++i) {
        int row = bm + ty * 4 + i;
#pragma unroll
        for (int j = 0; j < 4; ++j) {
            int col = bn + tx * 4 + j;
            float v = acc[i][j] + bias[col];
            if (relu) v = fmaxf(v, 0.f);
            C[(size_t)row * N + col] = v;
        }
    }
}

// ---------------------------------------------------------------- attention
// K == Q (kq_same).  Q,V: [B,S,E] head h at cols h*32..h*32+31.  Ctx: [B,S,E].
// strict==1: mask j<i (row 0 -> uniform over all 512 keys, matching jax).
#define AQT 128
#define AKT 128
__global__ __launch_bounds__(128) void attn_kernel(
    const float* __restrict__ Q, const float* __restrict__ V,
    float* __restrict__ Ctx, int strict)
{
    __shared__ float Ks[AKT][33];
    __shared__ float Vs[AKT][33];
    int blk = blockIdx.x;
    int qt = blk & 3;
    int h  = (blk >> 2) & 7;
    int b  = blk >> 5;
    int tid = threadIdx.x;
    int i = qt * AQT + tid;

    float q[32], ctx[32];
    const float* qrow = Q + ((size_t)b * CS + i) * CE + h * 32;
#pragma unroll
    for (int d = 0; d < 32; d += 4) {
        float4 v = *reinterpret_cast<const float4*>(&qrow[d]);
        q[d] = v.x; q[d + 1] = v.y; q[d + 2] = v.z; q[d + 3] = v.w;
    }
#pragma unroll
    for (int d = 0; d < 32; ++d) ctx[d] = 0.f;

    float m = -INFINITY, l = 0.f;
    int jmax = strict ? i : i + 1;       // exclusive bound of unmasked keys
    bool uniform = (jmax == 0);          // strict row 0: uniform attention

    int ntiles = qt + 1;
    if (strict && qt == 0) ntiles = 4;   // block holds the uniform thread

    for (int tile = 0; tile < ntiles; ++tile) {
        int j0 = tile * AKT;
        // cooperative load of K,V tile (coalesced)
        for (int r = 0; r < 32; ++r) {
            int flat = tid + 128 * r;    // 0..4095
            int j = flat >> 5, d = flat & 31;
            size_t g = ((size_t)b * CS + j0 + j) * CE + h * 32 + d;
            Ks[j][d] = Q[g];
            Vs[j][d] = V[g];
        }
        __syncthreads();
        int jend = uniform ? AKT : (jmax - j0 < AKT ? jmax - j0 : AKT);
        for (int j = 0; j < jend; ++j) {
            float s = 0.f;
#pragma unroll
            for (int d = 0; d < 32; ++d) s += q[d] * Ks[j][d];
            s *= SCALE;
            if (uniform) s = 0.f;
            if (s <= m) {
                float p = __expf(s - m);
                l += p;
#pragma unroll
                for (int d = 0; d < 32; ++d) ctx[d] += p * Vs[j][d];
            } else {
                float sc = __expf(m - s);
                l = l * sc + 1.f;
#pragma unroll
                for (int d = 0; d < 32; ++d) ctx[d] = ctx[d] * sc + Vs[j][d];
                m = s;
            }
        }
        __syncthreads();
    }
    float inv = 1.f / l;
    float* orow = Ctx + ((size_t)b * CS + i) * CE + h * 32;
#pragma unroll
    for (int d = 0; d < 32; d += 4) {
        float4 v;
        v.x = ctx[d] * inv; v.y = ctx[d + 1] * inv;
        v.z = ctx[d + 2] * inv; v.w = ctx[d + 3] * inv;
        *reinterpret_cast<float4*>(&orow[d]) = v;
    }
}

// ---------------------------------------------------------------- router gate
// One wave per token: logits = q_in @ Wg  (E x 6); keep top-4 (stable ties),
// zero the dropped dynamic heads of Ctx in place.  Heads 0,1 always kept.
__global__ __launch_bounds__(64) void gate_kernel(
    const float* __restrict__ qin, const float* __restrict__ Wg,
    float* __restrict__ Ctx)
{
    int t = blockIdx.x;
    int lane = threadIdx.x;
    const float* q = qin + (size_t)t * CE;
    float p[CNDYN] = {};
#pragma unroll
    for (int r = 0; r < 4; ++r) {
        int e = lane + r * 64;
        float qe = q[e];
        const float* wg = &Wg[(size_t)e * CNDYN];
#pragma unroll
        for (int j = 0; j < CNDYN; ++j) p[j] += qe * wg[j];
    }
#pragma unroll
    for (int o = 32; o > 0; o >>= 1)
#pragma unroll
        for (int j = 0; j < CNDYN; ++j) p[j] += __shfl_down(p[j], o);
    int mask = 3;                        // shared heads 0,1
    if (lane == 0) {
        for (int j = 0; j < CNDYN; ++j) {
            int rank = 0;
            for (int k = 0; k < CNDYN; ++k)
                if (p[k] > p[j] || (p[k] == p[j] && k < j)) rank++;
            if (rank < 4) mask |= 1 << (2 + j);
        }
    }
    mask = __shfl(mask, 0);
    float* c = Ctx + (size_t)t * CE;
#pragma unroll
    for (int r = 0; r < 4; ++r) {
        int e = lane + r * 64;
        int hh = e >> 5;
        if (!((mask >> hh) & 1)) c[e] = 0.f;
    }
}

// ---------------------------------------------------------------- residual+LN
__global__ __launch_bounds__(256) void add_ln(
    const float* __restrict__ A, const float* __restrict__ Bv,
    const float* __restrict__ g, const float* __restrict__ bb,
    float* __restrict__ O)
{
    __shared__ float red[8];
    int t = blockIdx.x, e = threadIdx.x;
    size_t base = (size_t)t * CE;
    float v = A[base + e] + Bv[base + e];
    float s = v;
#pragma unroll
    for (int o = 32; o > 0; o >>= 1) s += __shfl_down(s, o);
    int wid = e >> 6, lane = e & 63;
    if (lane == 0) red[wid] = s;
    __syncthreads();
    if (e == 0) red[4] = (red[0] + red[1] + red[2] + red[3]) * (1.f / CE);
    __syncthreads();
    float mean = red[4];
    float d = v - mean;
    float s2 = d * d;
#pragma unroll
    for (int o = 32; o > 0; o >>= 1) s2 += __shfl_down(s2, o);
    if (lane == 0) red[wid] = s2;
    __syncthreads();
    if (e == 0) red[5] = (red[0] + red[1] + red[2] + red[3]) * (1.f / CE);
    __syncthreads();
    float var = red[5];
    O[base + e] = d * rsqrtf(var + 1e-5f) * g[e] + bb[e];
}

// ---------------------------------------------------------------- concat
__global__ __launch_bounds__(256) void concat_kernel(
    const float* __restrict__ x, const float* __restrict__ qe,
    float* __restrict__ cat)
{
    int t = blockIdx.x, e = threadIdx.x;
    cat[(size_t)t * 512 + e]       = x[(size_t)t * CE + e];
    cat[(size_t)t * 512 + 256 + e] = qe[(size_t)t * CE + e];
}

// ---------------------------------------------------------------- final dot + sigmoid
__global__ __launch_bounds__(64) void final_kernel(
    const float* __restrict__ H2, const float* __restrict__ W3,
    const float* __restrict__ b3, float* __restrict__ out)
{
    int t = blockIdx.x, lane = threadIdx.x;
    const float* h = H2 + (size_t)t * CE;
    float s = 0.f;
#pragma unroll
    for (int r = 0; r < 4; ++r) {
        int e = lane + r * 64;
        s += h[e] * W3[e];
    }
#pragma unroll
    for (int o = 32; o > 0; o >>= 1) s += __shfl_down(s, o);
    if (lane == 0) {
        float v = 1.f / (1.f + __expf(-(s + b3[0])));
        int b = t >> 9, si = t & 511;
        if (si > 0) out[(size_t)b * (CS - 1) + si - 1] = v;
    }
}

// ---------------------------------------------------------------- driver
extern "C" void kernel_launch(void* const* d_in, const int* in_sizes, int n_in,
                              void* d_out, int out_size, void* d_ws, size_t ws_size,
                              hipStream_t stream)
{
    const int* skills    = (const int*)d_in[0];
    const int* responses = (const int*)d_in[1];
    const int* questions = (const int*)d_in[2];
    const float* q_embed       = (const float*)d_in[4];
    const float* qa_embed      = (const float*)d_in[5];
    const float* q_embed_diff  = (const float*)d_in[6];
    const float* qa_embed_diff = (const float*)d_in[7];
    const float* difficult     = (const float*)d_in[8];
    const float* Wq = (const float*)d_in[9];  const float* bq = (const float*)d_in[10];
    const float* Wv = (const float*)d_in[11]; const float* bv = (const float*)d_in[12];
    const float* Wo = (const float*)d_in[13]; const float* bo = (const float*)d_in[14];
    const float* Wg = (const float*)d_in[15];
    const float* ln1g = (const float*)d_in[16]; const float* ln1b = (const float*)d_in[17];
    const float* ln2g = (const float*)d_in[18]; const float* ln2b = (const float*)d_in[19];
    const float* fW1 = (const float*)d_in[20]; const float* fb1 = (const float*)d_in[21];
    const float* fW2 = (const float*)d_in[22]; const float* fb2 = (const float*)d_in[23];
    const float* oW1 = (const float*)d_in[24]; const float* ob1 = (const float*)d_in[25];
    const float* oW2 = (const float*)d_in[26]; const float* ob2 = (const float*)d_in[27];
    const float* oW3 = (const float*)d_in[28]; const float* ob3 = (const float*)d_in[29];
    float* out = (float*)d_out;

    char* ws = (char*)d_ws;
    const size_t R = (size_t)CT * CE * sizeof(float);   // 8 MB per region
    float* q_emb = (float*)(ws + 0 * R);
    float* xb    = (float*)(ws + 1 * R);
    float* yb    = (float*)(ws + 2 * R);
    float* S0    = (float*)(ws + 3 * R);
    float* S1    = (float*)(ws + 4 * R);
    float* S2    = (float*)(ws + 5 * R);   // S2..S3 form a 16MB region for H1
    (void)in_sizes; (void)n_in; (void)out_size; (void)ws_size;

    embed_kernel<<<CT, 256, 0, stream>>>(skills, responses, questions,
        q_embed, qa_embed, q_embed_diff, qa_embed_diff, difficult, q_emb, yb);
    hipMemcpyAsync(xb, q_emb, R, hipMemcpyDeviceToDevice, stream);

    dim3 g256(CE / TBN, CT / TBM);   // (4,128)

    auto layer = [&](int li, const float* qin, const float* vin, float* outc, int strict) {
        const size_t EE = (size_t)CE * CE;
        gemm_bias<<<g256, 256, 0, stream>>>(qin, Wq + li * EE, bq + (size_t)li * CE, S0, CT, CE, CE, 0);
        gemm_bias<<<g256, 256, 0, stream>>>(vin, Wv + li * EE, bv + (size_t)li * CE, S1, CT, CE, CE, 0);
        attn_kernel<<<CB * CH * 4, 128, 0, stream>>>(S0, S1, S2, strict);
        gate_kernel<<<CT, 64, 0, stream>>>(qin, Wg + (size_t)li * CE * CNDYN, S2);
        gemm_bias<<<g256, 256, 0, stream>>>(S2, Wo + li * EE, bo + (size_t)li * CE, S0, CT, CE, CE, 0);
        add_ln<<<CT, 256, 0, stream>>>(qin, S0, ln1g + (size_t)li * CE, ln1b + (size_t)li * CE, S1);
        gemm_bias<<<g256, 256, 0, stream>>>(S1, fW1 + li * EE, fb1 + (size_t)li * CE, S2, CT, CE, CE, 1);
        gemm_bias<<<g256, 256, 0, stream>>>(S2, fW2 + li * EE, fb2 + (size_t)li * CE, S0, CT, CE, CE, 0);
        add_ln<<<CT, 256, 0, stream>>>(S1, S0, ln2g + (size_t)li * CE, ln2b + (size_t)li * CE, outc);
    };

    for (int i = 0; i < 4; ++i) layer(i, yb, yb, yb, 0);
    int li = 4;
    for (int r = 0; r < 4; ++r) {
        layer(li, xb, xb, xb, 0); li++;
        layer(li, xb, yb, xb, 1); li++;   // q=x, k=x, v=y, strict mask
    }

    // output MLP: cat = [x, q_emb] (in S0..S1), H1 = relu(cat@W1+b1) (S2..S3),
    // H2 = relu(H1@W2+b2) -> xb, out = sigmoid(H2@W3+b3)[:,1:]
    concat_kernel<<<CT, 256, 0, stream>>>(xb, q_emb, S0);
    gemm_bias<<<dim3(512 / TBN, CT / TBM), 256, 0, stream>>>(S0, oW1, ob1, S2, CT, 512, 512, 1);
    gemm_bias<<<dim3(256 / TBN, CT / TBM), 256, 0, stream>>>(S2, oW2, ob2, xb, CT, 256, 512, 1);
    final_kernel<<<CT, 64, 0, stream>>>(xb, oW3, ob3, out);
}

// Round 4
// 3802.171 us; speedup vs baseline: 1.3882x; 1.3882x over previous
//
#include <hip/hip_runtime.h>
#include <hip/hip_bf16.h>

// Problem constants
constexpr int CB = 16, CS = 512, CE = 256, CH = 8, CDK = 32;
constexpr int CNDYN = 6;
constexpr int CT = CB * CS;          // 8192 tokens
constexpr float SCALE = 0.17677669529663687f; // 1/sqrt(32)

// ---------------------------------------------------------------- embeddings
__global__ __launch_bounds__(256) void embed_kernel(
    const int* __restrict__ skills, const int* __restrict__ responses,
    const int* __restrict__ questions,
    const float* __restrict__ q_embed, const float* __restrict__ qa_embed,
    const float* __restrict__ q_embed_diff, const float* __restrict__ qa_embed_diff,
    const float* __restrict__ difficult,
    float* __restrict__ q_emb, float* __restrict__ qa_emb)
{
    int t = blockIdx.x;
    int e = threadIdx.x;
    int sk = skills[t];
    int r  = responses[t];
    r = (r > -1) ? r : 0;            // masked_r
    float pid = difficult[questions[t]];
    float qe  = q_embed[(size_t)sk * CE + e];
    float qd  = q_embed_diff[(size_t)sk * CE + e];
    float qv  = qe + pid * qd;
    float qae = qe + qa_embed[(size_t)r * CE + e];
    float qad = qa_embed_diff[((size_t)sk + 1000 * r) * CE + e];
    float qav = qae + pid * (qad + qd);
    q_emb[(size_t)t * CE + e]  = qv;
    qa_emb[(size_t)t * CE + e] = qav;
}

// ---------------------------------------------------------------- generic GEMM
// C[M,N] = A[M,K] @ W[K,N] + bias, optional relu.  M%64==0, N%64==0, K%16==0.
#define TBM 64
#define TBN 64
#define TBK 16
__global__ __launch_bounds__(256) void gemm_bias(
    const float* __restrict__ A, const float* __restrict__ W,
    const float* __restrict__ bias, float* __restrict__ C,
    int M, int N, int K, int relu)
{
    __shared__ float As[TBK][TBM + 1];
    __shared__ float Ws[TBK][TBN];
    int tid = threadIdx.x;
    int bm = blockIdx.y * TBM;
    int bn = blockIdx.x * TBN;
    int tx = tid & 15, ty = tid >> 4;
    float acc[4][4] = {};
    for (int k0 = 0; k0 < K; k0 += TBK) {
        {   // A tile: 64x16
            int idx = tid * 4;
            int m = idx >> 4, k = idx & 15;
            float4 v = *reinterpret_cast<const float4*>(&A[(size_t)(bm + m) * K + k0 + k]);
            As[k + 0][m] = v.x; As[k + 1][m] = v.y; As[k + 2][m] = v.z; As[k + 3][m] = v.w;
        }
        {   // W tile: 16x64
            int idx = tid * 4;
            int k = idx >> 6, n = idx & 63;
            float4 v = *reinterpret_cast<const float4*>(&W[(size_t)(k0 + k) * N + bn + n]);
            *reinterpret_cast<float4*>(&Ws[k][n]) = v;
        }
        __syncthreads();
#pragma unroll
        for (int k = 0; k < TBK; ++k) {
            float a[4], w[4];
#pragma unroll
            for (int i = 0; i < 4; ++i) a[i] = As[k][ty * 4 + i];
#pragma unroll
            for (int j = 0; j < 4; ++j) w[j] = Ws[k][tx * 4 + j];
#pragma unroll
            for (int i = 0; i < 4; ++i)
#pragma unroll
                for (int j = 0; j < 4; ++j) acc[i][j] += a[i] * w[j];
        }
        __syncthreads();
    }
#pragma unroll
    for (int i = 0; i < 4; ++i) {
        int row = bm + ty * 4 + i;
#pragma unroll
        for (int j = 0; j < 4; ++j) {
            int col = bn + tx * 4 + j;
            float v = acc[i][j] + bias[col];
            if (relu) v = fmaxf(v, 0.f);
            C[(size_t)row * N + col] = v;
        }
    }
}

// ---------------------------------------------------------------- attention
// K == Q (kq_same).  Q,V: [B,S,E] head h at cols h*32..h*32+31.  Ctx: [B,S,E].
// strict==1: mask j<i (row 0 -> uniform over all 512 keys, matching jax).
// Block: 256 threads = 64 queries x 4 key-split partitions. Each partition
// keeps a private online-softmax state over keys j === p (mod 4); states are
// merged through LDS at the end.
#define AQT 64
#define AKT 128
__global__ __launch_bounds__(256) void attn_kernel(
    const float* __restrict__ Q, const float* __restrict__ V,
    float* __restrict__ Ctx, int strict)
{
    // union: K/V tiles (2*128*33 = 8448 floats) vs merge area (64*4*34 = 8704)
    __shared__ float lds[AQT * 4 * 34];
    float (*Ks)[33] = reinterpret_cast<float (*)[33]>(lds);
    float (*Vs)[33] = reinterpret_cast<float (*)[33]>(lds + AKT * 33);

    int blk = blockIdx.x;
    int qt = blk & 7;
    int h  = (blk >> 3) & 7;
    int b  = blk >> 6;
    int tid = threadIdx.x;
    int q  = tid >> 2;          // query within block (0..63)
    int p  = tid & 3;           // key partition (0..3)
    int i  = qt * AQT + q;      // global query row in sequence

    float qreg[32], ctx[32];
    const float* qrow = Q + ((size_t)b * CS + i) * CE + h * 32;
#pragma unroll
    for (int d = 0; d < 32; d += 4) {
        float4 v = *reinterpret_cast<const float4*>(&qrow[d]);
        qreg[d] = v.x; qreg[d + 1] = v.y; qreg[d + 2] = v.z; qreg[d + 3] = v.w;
    }
#pragma unroll
    for (int d = 0; d < 32; ++d) ctx[d] = 0.f;

    float m = -INFINITY, l = 0.f;
    int jmax = strict ? i : i + 1;       // exclusive bound of unmasked keys
    bool uniform = (jmax == 0);          // strict row 0: uniform attention

    int bound = strict ? (qt * AQT + AQT - 1) : (qt * AQT + AQT);
    int ntiles = (bound + AKT - 1) / AKT;
    if (ntiles < 1) ntiles = 1;
    if (strict && qt == 0) ntiles = CS / AKT;  // block holds the uniform row

    for (int tile = 0; tile < ntiles; ++tile) {
        int j0 = tile * AKT;
        // cooperative load of K,V tile: 128 rows x 32 dims, float4 per thread x4
#pragma unroll
        for (int r = 0; r < 4; ++r) {
            int flat = (r * 256 + tid) * 4;     // 0..4092
            int j = flat >> 5, d = flat & 31;
            size_t g = ((size_t)b * CS + j0 + j) * CE + h * 32 + d;
            float4 kv = *reinterpret_cast<const float4*>(&Q[g]);
            float4 vv = *reinterpret_cast<const float4*>(&V[g]);
            Ks[j][d] = kv.x; Ks[j][d+1] = kv.y; Ks[j][d+2] = kv.z; Ks[j][d+3] = kv.w;
            Vs[j][d] = vv.x; Vs[j][d+1] = vv.y; Vs[j][d+2] = vv.z; Vs[j][d+3] = vv.w;
        }
        __syncthreads();
        int jloc = uniform ? AKT : (jmax - j0 < AKT ? jmax - j0 : AKT);
        for (int j = p; j < jloc; j += 4) {
            float s0 = 0.f, s1 = 0.f, s2 = 0.f, s3 = 0.f;
#pragma unroll
            for (int d = 0; d < 32; d += 4) {
                s0 += qreg[d]     * Ks[j][d];
                s1 += qreg[d + 1] * Ks[j][d + 1];
                s2 += qreg[d + 2] * Ks[j][d + 2];
                s3 += qreg[d + 3] * Ks[j][d + 3];
            }
            float s = ((s0 + s1) + (s2 + s3)) * SCALE;
            if (uniform) s = 0.f;
            if (s <= m) {
                float pw = __expf(s - m);
                l += pw;
#pragma unroll
                for (int d = 0; d < 32; ++d) ctx[d] += pw * Vs[j][d];
            } else {
                float sc = __expf(m - s);
                l = l * sc + 1.f;
#pragma unroll
                for (int d = 0; d < 32; ++d) ctx[d] = ctx[d] * sc + Vs[j][d];
                m = s;
            }
        }
        __syncthreads();
    }

    // merge the 4 partial states per query through LDS
    float* st = lds + (size_t)tid * 34;
    st[0] = m; st[1] = l;
#pragma unroll
    for (int d = 0; d < 32; ++d) st[2 + d] = ctx[d];
    __syncthreads();
    const float* s0p = lds + (size_t)(q * 4) * 34;
    float m0 = s0p[0], m1 = s0p[34], m2 = s0p[68], m3 = s0p[102];
    float mm = fmaxf(fmaxf(m0, m1), fmaxf(m2, m3));
    float e0 = __expf(m0 - mm), e1 = __expf(m1 - mm);
    float e2 = __expf(m2 - mm), e3 = __expf(m3 - mm);
    float ll = s0p[1] * e0 + s0p[35] * e1 + s0p[69] * e2 + s0p[103] * e3;
    float inv = 1.f / ll;
    float o[8];
#pragma unroll
    for (int k = 0; k < 8; ++k) {
        int d = p * 8 + k;
        o[k] = (s0p[2 + d] * e0 + s0p[36 + d] * e1 +
                s0p[70 + d] * e2 + s0p[104 + d] * e3) * inv;
    }
    float* orow = Ctx + ((size_t)b * CS + i) * CE + h * 32 + p * 8;
    float4 w0 = {o[0], o[1], o[2], o[3]};
    float4 w1 = {o[4], o[5], o[6], o[7]};
    *reinterpret_cast<float4*>(orow)     = w0;
    *reinterpret_cast<float4*>(orow + 4) = w1;
}

// ---------------------------------------------------------------- router gate
// One wave per token: logits = q_in @ Wg  (E x 6); keep top-4 (stable ties),
// zero the dropped dynamic heads of Ctx in place.  Heads 0,1 always kept.
__global__ __launch_bounds__(64) void gate_kernel(
    const float* __restrict__ qin, const float* __restrict__ Wg,
    float* __restrict__ Ctx)
{
    int t = blockIdx.x;
    int lane = threadIdx.x;
    const float* q = qin + (size_t)t * CE;
    float p[CNDYN] = {};
#pragma unroll
    for (int r = 0; r < 4; ++r) {
        int e = lane + r * 64;
        float qe = q[e];
        const float* wg = &Wg[(size_t)e * CNDYN];
#pragma unroll
        for (int j = 0; j < CNDYN; ++j) p[j] += qe * wg[j];
    }
#pragma unroll
    for (int o = 32; o > 0; o >>= 1)
#pragma unroll
        for (int j = 0; j < CNDYN; ++j) p[j] += __shfl_down(p[j], o);
    int mask = 3;                        // shared heads 0,1
    if (lane == 0) {
        for (int j = 0; j < CNDYN; ++j) {
            int rank = 0;
            for (int k = 0; k < CNDYN; ++k)
                if (p[k] > p[j] || (p[k] == p[j] && k < j)) rank++;
            if (rank < 4) mask |= 1 << (2 + j);
        }
    }
    mask = __shfl(mask, 0);
    float* c = Ctx + (size_t)t * CE;
#pragma unroll
    for (int r = 0; r < 4; ++r) {
        int e = lane + r * 64;
        int hh = e >> 5;
        if (!((mask >> hh) & 1)) c[e] = 0.f;
    }
}

// ---------------------------------------------------------------- residual+LN
__global__ __launch_bounds__(256) void add_ln(
    const float* __restrict__ A, const float* __restrict__ Bv,
    const float* __restrict__ g, const float* __restrict__ bb,
    float* __restrict__ O)
{
    __shared__ float red[8];
    int t = blockIdx.x, e = threadIdx.x;
    size_t base = (size_t)t * CE;
    float v = A[base + e] + Bv[base + e];
    float s = v;
#pragma unroll
    for (int o = 32; o > 0; o >>= 1) s += __shfl_down(s, o);
    int wid = e >> 6, lane = e & 63;
    if (lane == 0) red[wid] = s;
    __syncthreads();
    if (e == 0) red[4] = (red[0] + red[1] + red[2] + red[3]) * (1.f / CE);
    __syncthreads();
    float mean = red[4];
    float d = v - mean;
    float s2 = d * d;
#pragma unroll
    for (int o = 32; o > 0; o >>= 1) s2 += __shfl_down(s2, o);
    if (lane == 0) red[wid] = s2;
    __syncthreads();
    if (e == 0) red[5] = (red[0] + red[1] + red[2] + red[3]) * (1.f / CE);
    __syncthreads();
    float var = red[5];
    O[base + e] = d * rsqrtf(var + 1e-5f) * g[e] + bb[e];
}

// ---------------------------------------------------------------- concat
__global__ __launch_bounds__(256) void concat_kernel(
    const float* __restrict__ x, const float* __restrict__ qe,
    float* __restrict__ cat)
{
    int t = blockIdx.x, e = threadIdx.x;
    cat[(size_t)t * 512 + e]       = x[(size_t)t * CE + e];
    cat[(size_t)t * 512 + 256 + e] = qe[(size_t)t * CE + e];
}

// ---------------------------------------------------------------- final dot + sigmoid
__global__ __launch_bounds__(64) void final_kernel(
    const float* __restrict__ H2, const float* __restrict__ W3,
    const float* __restrict__ b3, float* __restrict__ out)
{
    int t = blockIdx.x, lane = threadIdx.x;
    const float* h = H2 + (size_t)t * CE;
    float s = 0.f;
#pragma unroll
    for (int r = 0; r < 4; ++r) {
        int e = lane + r * 64;
        s += h[e] * W3[e];
    }
#pragma unroll
    for (int o = 32; o > 0; o >>= 1) s += __shfl_down(s, o);
    if (lane == 0) {
        float v = 1.f / (1.f + __expf(-(s + b3[0])));
        int b = t >> 9, si = t & 511;
        if (si > 0) out[(size_t)b * (CS - 1) + si - 1] = v;
    }
}

// ---------------------------------------------------------------- driver
extern "C" void kernel_launch(void* const* d_in, const int* in_sizes, int n_in,
                              void* d_out, int out_size, void* d_ws, size_t ws_size,
                              hipStream_t stream)
{
    const int* skills    = (const int*)d_in[0];
    const int* responses = (const int*)d_in[1];
    const int* questions = (const int*)d_in[2];
    const float* q_embed       = (const float*)d_in[4];
    const float* qa_embed      = (const float*)d_in[5];
    const float* q_embed_diff  = (const float*)d_in[6];
    const float* qa_embed_diff = (const float*)d_in[7];
    const float* difficult     = (const float*)d_in[8];
    const float* Wq = (const float*)d_in[9];  const float* bq = (const float*)d_in[10];
    const float* Wv = (const float*)d_in[11]; const float* bv = (const float*)d_in[12];
    const float* Wo = (const float*)d_in[13]; const float* bo = (const float*)d_in[14];
    const float* Wg = (const float*)d_in[15];
    const float* ln1g = (const float*)d_in[16]; const float* ln1b = (const float*)d_in[17];
    const float* ln2g = (const float*)d_in[18]; const float* ln2b = (const float*)d_in[19];
    const float* fW1 = (const float*)d_in[20]; const float* fb1 = (const float*)d_in[21];
    const float* fW2 = (const float*)d_in[22]; const float* fb2 = (const float*)d_in[23];
    const float* oW1 = (const float*)d_in[24]; const float* ob1 = (const float*)d_in[25];
    const float* oW2 = (const float*)d_in[26]; const float* ob2 = (const float*)d_in[27];
    const float* oW3 = (const float*)d_in[28]; const float* ob3 = (const float*)d_in[29];
    float* out = (float*)d_out;

    char* ws = (char*)d_ws;
    const size_t R = (size_t)CT * CE * sizeof(float);   // 8 MB per region
    float* q_emb = (float*)(ws + 0 * R);
    float* xb    = (float*)(ws + 1 * R);
    float* yb    = (float*)(ws + 2 * R);
    float* S0    = (float*)(ws + 3 * R);
    float* S1    = (float*)(ws + 4 * R);
    float* S2    = (float*)(ws + 5 * R);   // S2..S3 form a 16MB region for H1
    (void)in_sizes; (void)n_in; (void)out_size; (void)ws_size;

    embed_kernel<<<CT, 256, 0, stream>>>(skills, responses, questions,
        q_embed, qa_embed, q_embed_diff, qa_embed_diff, difficult, q_emb, yb);
    hipMemcpyAsync(xb, q_emb, R, hipMemcpyDeviceToDevice, stream);

    dim3 g256(CE / TBN, CT / TBM);   // (4,128)

    auto layer = [&](int li, const float* qin, const float* vin, float* outc, int strict) {
        const size_t EE = (size_t)CE * CE;
        gemm_bias<<<g256, 256, 0, stream>>>(qin, Wq + li * EE, bq + (size_t)li * CE, S0, CT, CE, CE, 0);
        gemm_bias<<<g256, 256, 0, stream>>>(vin, Wv + li * EE, bv + (size_t)li * CE, S1, CT, CE, CE, 0);
        attn_kernel<<<CB * CH * (CS / AQT), 256, 0, stream>>>(S0, S1, S2, strict);
        gate_kernel<<<CT, 64, 0, stream>>>(qin, Wg + (size_t)li * CE * CNDYN, S2);
        gemm_bias<<<g256, 256, 0, stream>>>(S2, Wo + li * EE, bo + (size_t)li * CE, S0, CT, CE, CE, 0);
        add_ln<<<CT, 256, 0, stream>>>(qin, S0, ln1g + (size_t)li * CE, ln1b + (size_t)li * CE, S1);
        gemm_bias<<<g256, 256, 0, stream>>>(S1, fW1 + li * EE, fb1 + (size_t)li * CE, S2, CT, CE, CE, 1);
        gemm_bias<<<g256, 256, 0, stream>>>(S2, fW2 + li * EE, fb2 + (size_t)li * CE, S0, CT, CE, CE, 0);
        add_ln<<<CT, 256, 0, stream>>>(S1, S0, ln2g + (size_t)li * CE, ln2b + (size_t)li * CE, outc);
    };

    for (int i = 0; i < 4; ++i) layer(i, yb, yb, yb, 0);
    int li = 4;
    for (int r = 0; r < 4; ++r) {
        layer(li, xb, xb, xb, 0); li++;
        layer(li, xb, yb, xb, 1); li++;   // q=x, k=x, v=y, strict mask
    }

    // output MLP: cat = [x, q_emb] (in S0..S1), H1 = relu(cat@W1+b1) (S2..S3),
    // H2 = relu(H1@W2+b2) -> xb, out = sigmoid(H2@W3+b3)[:,1:]
    concat_kernel<<<CT, 256, 0, stream>>>(xb, q_emb, S0);
    gemm_bias<<<dim3(512 / TBN, CT / TBM), 256, 0, stream>>>(S0, oW1, ob1, S2, CT, 512, 512, 1);
    gemm_bias<<<dim3(256 / TBN, CT / TBM), 256, 0, stream>>>(S2, oW2, ob2, xb, CT, 256, 512, 1);
    final_kernel<<<CT, 64, 0, stream>>>(xb, oW3, ob3, out);
}

// Round 5
// 2060.860 us; speedup vs baseline: 2.5612x; 1.8449x over previous
//
#include <hip/hip_runtime.h>
#include <hip/hip_bf16.h>

// Problem constants
constexpr int CB = 16, CS = 512, CE = 256, CH = 8, CDK = 32;
constexpr int CNDYN = 6;
constexpr int CT = CB * CS;          // 8192 tokens
constexpr float SCALE = 0.17677669529663687f; // 1/sqrt(32)

typedef __bf16 bf16x8 __attribute__((ext_vector_type(8)));
typedef float f32x4 __attribute__((ext_vector_type(4)));

__device__ __forceinline__ unsigned short f2bf(float x) {
    union { float f; unsigned u; } v; v.f = x;
    unsigned r = v.u + 0x7fff + ((v.u >> 16) & 1);   // RNE
    return (unsigned short)(r >> 16);
}

// ---------------------------------------------------------------- embeddings
__global__ __launch_bounds__(256) void embed_kernel(
    const int* __restrict__ skills, const int* __restrict__ responses,
    const int* __restrict__ questions,
    const float* __restrict__ q_embed, const float* __restrict__ qa_embed,
    const float* __restrict__ q_embed_diff, const float* __restrict__ qa_embed_diff,
    const float* __restrict__ difficult,
    float* __restrict__ q_emb, float* __restrict__ qa_emb)
{
    int t = blockIdx.x;
    int e = threadIdx.x;
    int sk = skills[t];
    int r  = responses[t];
    r = (r > -1) ? r : 0;            // masked_r
    float pid = difficult[questions[t]];
    float qe  = q_embed[(size_t)sk * CE + e];
    float qd  = q_embed_diff[(size_t)sk * CE + e];
    float qv  = qe + pid * qd;
    float qae = qe + qa_embed[(size_t)r * CE + e];
    float qad = qa_embed_diff[((size_t)sk + 1000 * r) * CE + e];
    float qav = qae + pid * (qad + qd);
    q_emb[(size_t)t * CE + e]  = qv;
    qa_emb[(size_t)t * CE + e] = qav;
}

// ---------------------------------------------------------------- generic GEMM
// C[M,N] = A[M,K] @ W[K,N] + bias, optional relu.  M%64==0, N%64==0, K%16==0.
#define TBM 64
#define TBN 64
#define TBK 16
__global__ __launch_bounds__(256) void gemm_bias(
    const float* __restrict__ A, const float* __restrict__ W,
    const float* __restrict__ bias, float* __restrict__ C,
    int M, int N, int K, int relu)
{
    __shared__ float As[TBK][TBM + 1];
    __shared__ float Ws[TBK][TBN];
    int tid = threadIdx.x;
    int bm = blockIdx.y * TBM;
    int bn = blockIdx.x * TBN;
    int tx = tid & 15, ty = tid >> 4;
    float acc[4][4] = {};
    for (int k0 = 0; k0 < K; k0 += TBK) {
        {   // A tile: 64x16
            int idx = tid * 4;
            int m = idx >> 4, k = idx & 15;
            float4 v = *reinterpret_cast<const float4*>(&A[(size_t)(bm + m) * K + k0 + k]);
            As[k + 0][m] = v.x; As[k + 1][m] = v.y; As[k + 2][m] = v.z; As[k + 3][m] = v.w;
        }
        {   // W tile: 16x64
            int idx = tid * 4;
            int k = idx >> 6, n = idx & 63;
            float4 v = *reinterpret_cast<const float4*>(&W[(size_t)(k0 + k) * N + bn + n]);
            *reinterpret_cast<float4*>(&Ws[k][n]) = v;
        }
        __syncthreads();
#pragma unroll
        for (int k = 0; k < TBK; ++k) {
            float a[4], w[4];
#pragma unroll
            for (int i = 0; i < 4; ++i) a[i] = As[k][ty * 4 + i];
#pragma unroll
            for (int j = 0; j < 4; ++j) w[j] = Ws[k][tx * 4 + j];
#pragma unroll
            for (int i = 0; i < 4; ++i)
#pragma unroll
                for (int j = 0; j < 4; ++j) acc[i][j] += a[i] * w[j];
        }
        __syncthreads();
    }
#pragma unroll
    for (int i = 0; i < 4; ++i) {
        int row = bm + ty * 4 + i;
#pragma unroll
        for (int j = 0; j < 4; ++j) {
            int col = bn + tx * 4 + j;
            float v = acc[i][j] + bias[col];
            if (relu) v = fmaxf(v, 0.f);
            C[(size_t)row * N + col] = v;
        }
    }
}

// ---------------------------------------------------------------- attention (bf16 MFMA flash)
// K == Q (kq_same).  Q,V: [B,S,E], head h at cols h*32..h*32+31.  Ctx: [B,S,E].
// Block: 256 threads = 4 waves; each wave owns 16 queries; 64 queries/block.
// Per key-tile (64 keys): S^T = K @ Q^T via mfma_16x16x32_bf16 (D: col=query,
// row=key) -> online softmax (reg-local + shfl_xor 16/32) -> P[q][key] bf16 in
// LDS -> ctx^T += V^T @ P^T via mfma (V staged transposed).
// strict==1: mask key>=query; query 0 -> uniform over all 512 keys (s=0).
__global__ __launch_bounds__(256) void attn_mfma(
    const float* __restrict__ Q, const float* __restrict__ V,
    float* __restrict__ Ctx, int strict)
{
    __shared__ __attribute__((aligned(16))) unsigned short Qs[64][40];
    __shared__ __attribute__((aligned(16))) unsigned short Ks[64][40];
    __shared__ __attribute__((aligned(16))) unsigned short VTs[32][72];
    __shared__ __attribute__((aligned(16))) unsigned short Ps[4][16][72]; // per-wave; reused as f32 ctxbuf[16][36]

    int blk = blockIdx.x;
    int qt = blk & 7;
    int h  = (blk >> 3) & 7;
    int b  = blk >> 6;
    int tid = threadIdx.x;
    int w = tid >> 6, lane = tid & 63;
    int lo = lane & 15, hi = lane >> 4;
    int qbase = qt * 64;
    int qg = qbase + w * 16 + lo;            // this lane's query (D column)
    bool uni = strict && (qg == 0);          // jax: all-masked row -> uniform

    // ---- stage Q (bf16) ----
    {
        int row = tid >> 2, d0 = (tid & 3) * 8;
        const float* p = Q + ((size_t)b * CS + qbase + row) * CE + h * 32 + d0;
        float4 a = *reinterpret_cast<const float4*>(p);
        float4 c = *reinterpret_cast<const float4*>(p + 4);
        unsigned short* dst = &Qs[row][d0];
        dst[0]=f2bf(a.x); dst[1]=f2bf(a.y); dst[2]=f2bf(a.z); dst[3]=f2bf(a.w);
        dst[4]=f2bf(c.x); dst[5]=f2bf(c.y); dst[6]=f2bf(c.z); dst[7]=f2bf(c.w);
    }
    __syncthreads();
    bf16x8 qfrag = *reinterpret_cast<const bf16x8*>(&Qs[w * 16 + lo][hi * 8]);

    f32x4 ctx0 = {0.f,0.f,0.f,0.f}, ctx1 = {0.f,0.f,0.f,0.f};
    float m = -1e30f, l = 0.f;

    int ntiles = (strict && qt == 0) ? (CS / 64) : (qt + 1);
    for (int t = 0; t < ntiles; ++t) {
        int k64 = t * 64;
        // ---- stage K and V^T (bf16) ----
        {
            int row = tid >> 2, d0 = (tid & 3) * 8;
            const float* kp = Q + ((size_t)b * CS + k64 + row) * CE + h * 32 + d0;
            float4 a = *reinterpret_cast<const float4*>(kp);
            float4 c = *reinterpret_cast<const float4*>(kp + 4);
            unsigned short* dst = &Ks[row][d0];
            dst[0]=f2bf(a.x); dst[1]=f2bf(a.y); dst[2]=f2bf(a.z); dst[3]=f2bf(a.w);
            dst[4]=f2bf(c.x); dst[5]=f2bf(c.y); dst[6]=f2bf(c.z); dst[7]=f2bf(c.w);
            const float* vp = V + ((size_t)b * CS + k64 + row) * CE + h * 32 + d0;
            float4 va = *reinterpret_cast<const float4*>(vp);
            float4 vc = *reinterpret_cast<const float4*>(vp + 4);
            VTs[d0+0][row]=f2bf(va.x); VTs[d0+1][row]=f2bf(va.y);
            VTs[d0+2][row]=f2bf(va.z); VTs[d0+3][row]=f2bf(va.w);
            VTs[d0+4][row]=f2bf(vc.x); VTs[d0+5][row]=f2bf(vc.y);
            VTs[d0+6][row]=f2bf(vc.z); VTs[d0+7][row]=f2bf(vc.w);
        }
        __syncthreads();

        // ---- S^T tiles: 4 x mfma (16 keys x 16 queries, K=32 dims) ----
        f32x4 sacc[4];
#pragma unroll
        for (int kt = 0; kt < 4; ++kt) {
            bf16x8 kfrag = *reinterpret_cast<const bf16x8*>(&Ks[kt * 16 + lo][hi * 8]);
            f32x4 z = {0.f,0.f,0.f,0.f};
            sacc[kt] = __builtin_amdgcn_mfma_f32_16x16x32_bf16(kfrag, qfrag, z, 0, 0, 0);
        }
        // ---- mask + online softmax ----
        float sv[16];
        float mt = -1e30f;
#pragma unroll
        for (int kt = 0; kt < 4; ++kt)
#pragma unroll
            for (int r = 0; r < 4; ++r) {
                int kidx = k64 + kt * 16 + hi * 4 + r;
                float s = sacc[kt][r] * SCALE;
                bool valid = strict ? (kidx < qg) : (kidx <= qg);
                s = valid ? s : -1e30f;
                if (uni) s = 0.f;
                sv[kt * 4 + r] = s;
                mt = fmaxf(mt, s);
            }
        mt = fmaxf(mt, __shfl_xor(mt, 16));
        mt = fmaxf(mt, __shfl_xor(mt, 32));
        float mn = fmaxf(m, mt);
        float co = __expf(m - mn);
        float lt = 0.f;
#pragma unroll
        for (int i = 0; i < 16; ++i) {
            float p = __expf(sv[i] - mn);
            sv[i] = p;
            lt += p;
        }
        lt += __shfl_xor(lt, 16);
        lt += __shfl_xor(lt, 32);
        l = l * co + lt;
        m = mn;
#pragma unroll
        for (int r = 0; r < 4; ++r) { ctx0[r] *= co; ctx1[r] *= co; }
        // ---- write P[q][key] bf16 ----
#pragma unroll
        for (int kt = 0; kt < 4; ++kt) {
            unsigned short* pd = &Ps[w][lo][kt * 16 + hi * 4];
            pd[0] = f2bf(sv[kt * 4 + 0]); pd[1] = f2bf(sv[kt * 4 + 1]);
            pd[2] = f2bf(sv[kt * 4 + 2]); pd[3] = f2bf(sv[kt * 4 + 3]);
        }
        __syncthreads();
        // ---- ctx^T += V^T @ P^T : 2 d-tiles x 2 key-halves ----
#pragma unroll
        for (int kh = 0; kh < 2; ++kh) {
            bf16x8 pfrag = *reinterpret_cast<const bf16x8*>(&Ps[w][lo][kh * 32 + hi * 8]);
            bf16x8 v0 = *reinterpret_cast<const bf16x8*>(&VTs[lo][kh * 32 + hi * 8]);
            bf16x8 v1 = *reinterpret_cast<const bf16x8*>(&VTs[16 + lo][kh * 32 + hi * 8]);
            ctx0 = __builtin_amdgcn_mfma_f32_16x16x32_bf16(v0, pfrag, ctx0, 0, 0, 0);
            ctx1 = __builtin_amdgcn_mfma_f32_16x16x32_bf16(v1, pfrag, ctx1, 0, 0, 0);
        }
        __syncthreads();
    }

    // ---- normalize + writeout via per-wave LDS transpose ----
    float inv = 1.f / l;
    float* cb = reinterpret_cast<float*>(&Ps[w][0][0]);   // [16 q][36 d]
#pragma unroll
    for (int r = 0; r < 4; ++r) {
        cb[lo * 36 + (hi * 4 + r)]      = ctx0[r] * inv;
        cb[lo * 36 + (16 + hi * 4 + r)] = ctx1[r] * inv;
    }
    __syncthreads();
    {
        int qloc = lane >> 2, d0 = (lane & 3) * 8;
        const float* src = cb + qloc * 36 + d0;
        float4 o0 = *reinterpret_cast<const float4*>(src);
        float4 o1 = *reinterpret_cast<const float4*>(src + 4);
        int i = qbase + w * 16 + qloc;
        float* op = Ctx + ((size_t)b * CS + i) * CE + h * 32 + d0;
        *reinterpret_cast<float4*>(op)     = o0;
        *reinterpret_cast<float4*>(op + 4) = o1;
    }
}

// ---------------------------------------------------------------- router gate
// One wave per token: logits = q_in @ Wg  (E x 6); keep top-4 (stable ties),
// zero the dropped dynamic heads of Ctx in place.  Heads 0,1 always kept.
__global__ __launch_bounds__(64) void gate_kernel(
    const float* __restrict__ qin, const float* __restrict__ Wg,
    float* __restrict__ Ctx)
{
    int t = blockIdx.x;
    int lane = threadIdx.x;
    const float* q = qin + (size_t)t * CE;
    float p[CNDYN] = {};
#pragma unroll
    for (int r = 0; r < 4; ++r) {
        int e = lane + r * 64;
        float qe = q[e];
        const float* wg = &Wg[(size_t)e * CNDYN];
#pragma unroll
        for (int j = 0; j < CNDYN; ++j) p[j] += qe * wg[j];
    }
#pragma unroll
    for (int o = 32; o > 0; o >>= 1)
#pragma unroll
        for (int j = 0; j < CNDYN; ++j) p[j] += __shfl_down(p[j], o);
    int mask = 3;                        // shared heads 0,1
    if (lane == 0) {
        for (int j = 0; j < CNDYN; ++j) {
            int rank = 0;
            for (int k = 0; k < CNDYN; ++k)
                if (p[k] > p[j] || (p[k] == p[j] && k < j)) rank++;
            if (rank < 4) mask |= 1 << (2 + j);
        }
    }
    mask = __shfl(mask, 0);
    float* c = Ctx + (size_t)t * CE;
#pragma unroll
    for (int r = 0; r < 4; ++r) {
        int e = lane + r * 64;
        int hh = e >> 5;
        if (!((mask >> hh) & 1)) c[e] = 0.f;
    }
}

// ---------------------------------------------------------------- residual+LN
__global__ __launch_bounds__(256) void add_ln(
    const float* __restrict__ A, const float* __restrict__ Bv,
    const float* __restrict__ g, const float* __restrict__ bb,
    float* __restrict__ O)
{
    __shared__ float red[8];
    int t = blockIdx.x, e = threadIdx.x;
    size_t base = (size_t)t * CE;
    float v = A[base + e] + Bv[base + e];
    float s = v;
#pragma unroll
    for (int o = 32; o > 0; o >>= 1) s += __shfl_down(s, o);
    int wid = e >> 6, lane = e & 63;
    if (lane == 0) red[wid] = s;
    __syncthreads();
    if (e == 0) red[4] = (red[0] + red[1] + red[2] + red[3]) * (1.f / CE);
    __syncthreads();
    float mean = red[4];
    float d = v - mean;
    float s2 = d * d;
#pragma unroll
    for (int o = 32; o > 0; o >>= 1) s2 += __shfl_down(s2, o);
    if (lane == 0) red[wid] = s2;
    __syncthreads();
    if (e == 0) red[5] = (red[0] + red[1] + red[2] + red[3]) * (1.f / CE);
    __syncthreads();
    float var = red[5];
    O[base + e] = d * rsqrtf(var + 1e-5f) * g[e] + bb[e];
}

// ---------------------------------------------------------------- concat
__global__ __launch_bounds__(256) void concat_kernel(
    const float* __restrict__ x, const float* __restrict__ qe,
    float* __restrict__ cat)
{
    int t = blockIdx.x, e = threadIdx.x;
    cat[(size_t)t * 512 + e]       = x[(size_t)t * CE + e];
    cat[(size_t)t * 512 + 256 + e] = qe[(size_t)t * CE + e];
}

// ---------------------------------------------------------------- final dot + sigmoid
__global__ __launch_bounds__(64) void final_kernel(
    const float* __restrict__ H2, const float* __restrict__ W3,
    const float* __restrict__ b3, float* __restrict__ out)
{
    int t = blockIdx.x, lane = threadIdx.x;
    const float* h = H2 + (size_t)t * CE;
    float s = 0.f;
#pragma unroll
    for (int r = 0; r < 4; ++r) {
        int e = lane + r * 64;
        s += h[e] * W3[e];
    }
#pragma unroll
    for (int o = 32; o > 0; o >>= 1) s += __shfl_down(s, o);
    if (lane == 0) {
        float v = 1.f / (1.f + __expf(-(s + b3[0])));
        int b = t >> 9, si = t & 511;
        if (si > 0) out[(size_t)b * (CS - 1) + si - 1] = v;
    }
}

// ---------------------------------------------------------------- driver
extern "C" void kernel_launch(void* const* d_in, const int* in_sizes, int n_in,
                              void* d_out, int out_size, void* d_ws, size_t ws_size,
                              hipStream_t stream)
{
    const int* skills    = (const int*)d_in[0];
    const int* responses = (const int*)d_in[1];
    const int* questions = (const int*)d_in[2];
    const float* q_embed       = (const float*)d_in[4];
    const float* qa_embed      = (const float*)d_in[5];
    const float* q_embed_diff  = (const float*)d_in[6];
    const float* qa_embed_diff = (const float*)d_in[7];
    const float* difficult     = (const float*)d_in[8];
    const float* Wq = (const float*)d_in[9];  const float* bq = (const float*)d_in[10];
    const float* Wv = (const float*)d_in[11]; const float* bv = (const float*)d_in[12];
    const float* Wo = (const float*)d_in[13]; const float* bo = (const float*)d_in[14];
    const float* Wg = (const float*)d_in[15];
    const float* ln1g = (const float*)d_in[16]; const float* ln1b = (const float*)d_in[17];
    const float* ln2g = (const float*)d_in[18]; const float* ln2b = (const float*)d_in[19];
    const float* fW1 = (const float*)d_in[20]; const float* fb1 = (const float*)d_in[21];
    const float* fW2 = (const float*)d_in[22]; const float* fb2 = (const float*)d_in[23];
    const float* oW1 = (const float*)d_in[24]; const float* ob1 = (const float*)d_in[25];
    const float* oW2 = (const float*)d_in[26]; const float* ob2 = (const float*)d_in[27];
    const float* oW3 = (const float*)d_in[28]; const float* ob3 = (const float*)d_in[29];
    float* out = (float*)d_out;

    char* ws = (char*)d_ws;
    const size_t R = (size_t)CT * CE * sizeof(float);   // 8 MB per region
    float* q_emb = (float*)(ws + 0 * R);
    float* xb    = (float*)(ws + 1 * R);
    float* yb    = (float*)(ws + 2 * R);
    float* S0    = (float*)(ws + 3 * R);
    float* S1    = (float*)(ws + 4 * R);
    float* S2    = (float*)(ws + 5 * R);   // S2..S3 form a 16MB region for H1
    (void)in_sizes; (void)n_in; (void)out_size; (void)ws_size;

    embed_kernel<<<CT, 256, 0, stream>>>(skills, responses, questions,
        q_embed, qa_embed, q_embed_diff, qa_embed_diff, difficult, q_emb, yb);
    hipMemcpyAsync(xb, q_emb, R, hipMemcpyDeviceToDevice, stream);

    dim3 g256(CE / TBN, CT / TBM);   // (4,128)

    auto layer = [&](int li, const float* qin, const float* vin, float* outc, int strict) {
        const size_t EE = (size_t)CE * CE;
        gemm_bias<<<g256, 256, 0, stream>>>(qin, Wq + li * EE, bq + (size_t)li * CE, S0, CT, CE, CE, 0);
        gemm_bias<<<g256, 256, 0, stream>>>(vin, Wv + li * EE, bv + (size_t)li * CE, S1, CT, CE, CE, 0);
        attn_mfma<<<CB * CH * 8, 256, 0, stream>>>(S0, S1, S2, strict);
        gate_kernel<<<CT, 64, 0, stream>>>(qin, Wg + (size_t)li * CE * CNDYN, S2);
        gemm_bias<<<g256, 256, 0, stream>>>(S2, Wo + li * EE, bo + (size_t)li * CE, S0, CT, CE, CE, 0);
        add_ln<<<CT, 256, 0, stream>>>(qin, S0, ln1g + (size_t)li * CE, ln1b + (size_t)li * CE, S1);
        gemm_bias<<<g256, 256, 0, stream>>>(S1, fW1 + li * EE, fb1 + (size_t)li * CE, S2, CT, CE, CE, 1);
        gemm_bias<<<g256, 256, 0, stream>>>(S2, fW2 + li * EE, fb2 + (size_t)li * CE, S0, CT, CE, CE, 0);
        add_ln<<<CT, 256, 0, stream>>>(S1, S0, ln2g + (size_t)li * CE, ln2b + (size_t)li * CE, outc);
    };

    for (int i = 0; i < 4; ++i) layer(i, yb, yb, yb, 0);
    int li = 4;
    for (int r = 0; r < 4; ++r) {
        layer(li, xb, xb, xb, 0); li++;
        layer(li, xb, yb, xb, 1); li++;   // q=x, k=x, v=y, strict mask
    }

    // output MLP: cat = [x, q_emb] (in S0..S1), H1 = relu(cat@W1+b1) (S2..S3),
    // H2 = relu(H1@W2+b2) -> xb, out = sigmoid(H2@W3+b3)[:,1:]
    concat_kernel<<<CT, 256, 0, stream>>>(xb, q_emb, S0);
    gemm_bias<<<dim3(512 / TBN, CT / TBM), 256, 0, stream>>>(S0, oW1, ob1, S2, CT, 512, 512, 1);
    gemm_bias<<<dim3(256 / TBN, CT / TBM), 256, 0, stream>>>(S2, oW2, ob2, xb, CT, 256, 512, 1);
    final_kernel<<<CT, 64, 0, stream>>>(xb, oW3, ob3, out);
}

// Round 6
// 1419.227 us; speedup vs baseline: 3.7190x; 1.4521x over previous
//
#include <hip/hip_runtime.h>
#include <hip/hip_bf16.h>

// Problem constants
constexpr int CB = 16, CS = 512, CE = 256, CH = 8, CDK = 32;
constexpr int CNDYN = 6;
constexpr int CT = CB * CS;          // 8192 tokens
constexpr float SCALE = 0.17677669529663687f; // 1/sqrt(32)

typedef __bf16 bf16x8 __attribute__((ext_vector_type(8)));
typedef float f32x4 __attribute__((ext_vector_type(4)));
typedef unsigned short u16x8 __attribute__((ext_vector_type(8)));

__device__ __forceinline__ unsigned short f2bf(float x) {
    union { float f; unsigned u; } v; v.f = x;
    unsigned r = v.u + 0x7fff + ((v.u >> 16) & 1);   // RNE
    return (unsigned short)(r >> 16);
}

// ---------------------------------------------------------------- embeddings
__global__ __launch_bounds__(256) void embed_kernel(
    const int* __restrict__ skills, const int* __restrict__ responses,
    const int* __restrict__ questions,
    const float* __restrict__ q_embed, const float* __restrict__ qa_embed,
    const float* __restrict__ q_embed_diff, const float* __restrict__ qa_embed_diff,
    const float* __restrict__ difficult,
    float* __restrict__ q_emb, float* __restrict__ qa_emb)
{
    int t = blockIdx.x;
    int e = threadIdx.x;
    int sk = skills[t];
    int r  = responses[t];
    r = (r > -1) ? r : 0;            // masked_r
    float pid = difficult[questions[t]];
    float qe  = q_embed[(size_t)sk * CE + e];
    float qd  = q_embed_diff[(size_t)sk * CE + e];
    float qv  = qe + pid * qd;
    float qae = qe + qa_embed[(size_t)r * CE + e];
    float qad = qa_embed_diff[((size_t)sk + 1000 * r) * CE + e];
    float qav = qae + pid * (qad + qd);
    q_emb[(size_t)t * CE + e]  = qv;
    qa_emb[(size_t)t * CE + e] = qav;
}

// ---------------------------------------------------------------- weight prep
// Transpose+convert fp32 [K][N] -> bf16 [N][K].  Block 256, one 64x64 tile.
__device__ __forceinline__ void transpose_tile(
    const float* __restrict__ src, unsigned short* __restrict__ dst, int K, int N)
{
    __shared__ unsigned short T[64][72];
    int k0 = blockIdx.y * 64, n0 = blockIdx.x * 64;
    int t = threadIdx.x;
    int kr = t >> 3, nsg = (t & 7) * 8;
#pragma unroll
    for (int rr = 0; rr < 64; rr += 32) {
        const float* p = src + (size_t)(k0 + kr + rr) * N + n0 + nsg;
        float4 a = *reinterpret_cast<const float4*>(p);
        float4 b = *reinterpret_cast<const float4*>(p + 4);
        int k = kr + rr;
        T[nsg + 0][k] = f2bf(a.x); T[nsg + 1][k] = f2bf(a.y);
        T[nsg + 2][k] = f2bf(a.z); T[nsg + 3][k] = f2bf(a.w);
        T[nsg + 4][k] = f2bf(b.x); T[nsg + 5][k] = f2bf(b.y);
        T[nsg + 6][k] = f2bf(b.z); T[nsg + 7][k] = f2bf(b.w);
    }
    __syncthreads();
    {
        int n = t >> 2, ks = (t & 3) * 16;
        unsigned short* dp = dst + (size_t)(n0 + n) * K + k0 + ks;
        *reinterpret_cast<u16x8*>(dp)     = *reinterpret_cast<const u16x8*>(&T[n][ks]);
        *reinterpret_cast<u16x8*>(dp + 8) = *reinterpret_cast<const u16x8*>(&T[n][ks + 8]);
    }
}

// grid (4,4,60): z -> {Wq,Wv,Wo,fW1,fW2}[z/12], layer z%12 (256x256 each)
__global__ __launch_bounds__(256) void prep_w_layers(
    const float* __restrict__ Wq, const float* __restrict__ Wv,
    const float* __restrict__ Wo, const float* __restrict__ W1,
    const float* __restrict__ W2, unsigned short* __restrict__ dst)
{
    int z = blockIdx.z;
    int which = z / 12, l = z % 12;
    const float* src;
    if      (which == 0) src = Wq;
    else if (which == 1) src = Wv;
    else if (which == 2) src = Wo;
    else if (which == 3) src = W1;
    else                 src = W2;
    transpose_tile(src + (size_t)l * 65536, dst + (size_t)z * 65536, 256, 256);
}

__global__ __launch_bounds__(256) void prep_w_one(
    const float* __restrict__ src, unsigned short* __restrict__ dst, int K, int N)
{
    transpose_tile(src, dst, K, N);
}

// ---------------------------------------------------------------- MFMA GEMM
// C[M,N] = A[M,K](fp32) @ W[K,N] + bias, W given as WT[N][K] bf16.
// 64x64 tile, BK=64, 4 waves (2x2), 32x32 per wave. fp32 accumulate.
__global__ __launch_bounds__(256) void gemm_mfma(
    const float* __restrict__ A, const unsigned short* __restrict__ WT,
    const float* __restrict__ bias, float* __restrict__ C,
    int M, int N, int K, int relu)
{
    __shared__ __attribute__((aligned(16))) unsigned short As[64][72];
    __shared__ __attribute__((aligned(16))) unsigned short Bs[64][72];
    int tid = threadIdx.x;
    int bm = blockIdx.y * 64, bn = blockIdx.x * 64;
    int w = tid >> 6, lane = tid & 63;
    int wr = w >> 1, wc = w & 1;
    int lo = lane & 15, hi = lane >> 4;
    int srow = tid >> 2, sseg = (tid & 3) * 16;
    f32x4 acc[2][2] = {};

    for (int kk = 0; kk < K; kk += 64) {
        {   // A: 64 rows x 64 k, fp32 -> bf16
            const float* ap = A + (size_t)(bm + srow) * K + kk + sseg;
            float4 a0 = *reinterpret_cast<const float4*>(ap);
            float4 a1 = *reinterpret_cast<const float4*>(ap + 4);
            float4 a2 = *reinterpret_cast<const float4*>(ap + 8);
            float4 a3 = *reinterpret_cast<const float4*>(ap + 12);
            u16x8 p0, p1;
            p0[0]=f2bf(a0.x); p0[1]=f2bf(a0.y); p0[2]=f2bf(a0.z); p0[3]=f2bf(a0.w);
            p0[4]=f2bf(a1.x); p0[5]=f2bf(a1.y); p0[6]=f2bf(a1.z); p0[7]=f2bf(a1.w);
            p1[0]=f2bf(a2.x); p1[1]=f2bf(a2.y); p1[2]=f2bf(a2.z); p1[3]=f2bf(a2.w);
            p1[4]=f2bf(a3.x); p1[5]=f2bf(a3.y); p1[6]=f2bf(a3.z); p1[7]=f2bf(a3.w);
            *reinterpret_cast<u16x8*>(&As[srow][sseg])     = p0;
            *reinterpret_cast<u16x8*>(&As[srow][sseg + 8]) = p1;
            // B: 64 n-rows x 64 k from bf16 WT
            const unsigned short* bp = WT + (size_t)(bn + srow) * K + kk + sseg;
            *reinterpret_cast<u16x8*>(&Bs[srow][sseg])     = *reinterpret_cast<const u16x8*>(bp);
            *reinterpret_cast<u16x8*>(&Bs[srow][sseg + 8]) = *reinterpret_cast<const u16x8*>(bp + 8);
        }
        __syncthreads();
#pragma unroll
        for (int ks = 0; ks < 2; ++ks) {
            bf16x8 a0 = *reinterpret_cast<const bf16x8*>(&As[wr * 32 + lo][ks * 32 + hi * 8]);
            bf16x8 a1 = *reinterpret_cast<const bf16x8*>(&As[wr * 32 + 16 + lo][ks * 32 + hi * 8]);
            bf16x8 b0 = *reinterpret_cast<const bf16x8*>(&Bs[wc * 32 + lo][ks * 32 + hi * 8]);
            bf16x8 b1 = *reinterpret_cast<const bf16x8*>(&Bs[wc * 32 + 16 + lo][ks * 32 + hi * 8]);
            acc[0][0] = __builtin_amdgcn_mfma_f32_16x16x32_bf16(a0, b0, acc[0][0], 0, 0, 0);
            acc[0][1] = __builtin_amdgcn_mfma_f32_16x16x32_bf16(a0, b1, acc[0][1], 0, 0, 0);
            acc[1][0] = __builtin_amdgcn_mfma_f32_16x16x32_bf16(a1, b0, acc[1][0], 0, 0, 0);
            acc[1][1] = __builtin_amdgcn_mfma_f32_16x16x32_bf16(a1, b1, acc[1][1], 0, 0, 0);
        }
        __syncthreads();
    }
#pragma unroll
    for (int i = 0; i < 2; ++i)
#pragma unroll
        for (int j = 0; j < 2; ++j) {
            int col = bn + wc * 32 + j * 16 + lo;
            float bv = bias[col];
#pragma unroll
            for (int r = 0; r < 4; ++r) {
                int row = bm + wr * 32 + i * 16 + hi * 4 + r;
                float v = acc[i][j][r] + bv;
                if (relu) v = fmaxf(v, 0.f);
                C[(size_t)row * N + col] = v;
            }
        }
}

// ---------------------------------------------------------------- attention (bf16 MFMA flash)
__global__ __launch_bounds__(256) void attn_mfma(
    const float* __restrict__ Q, const float* __restrict__ V,
    float* __restrict__ Ctx, int strict)
{
    __shared__ __attribute__((aligned(16))) unsigned short Qs[64][40];
    __shared__ __attribute__((aligned(16))) unsigned short Ks[64][40];
    __shared__ __attribute__((aligned(16))) unsigned short VTs[32][72];
    __shared__ __attribute__((aligned(16))) unsigned short Ps[4][16][72]; // per-wave; reused as f32 ctxbuf[16][36]

    int blk = blockIdx.x;
    int qt = blk & 7;
    int h  = (blk >> 3) & 7;
    int b  = blk >> 6;
    int tid = threadIdx.x;
    int w = tid >> 6, lane = tid & 63;
    int lo = lane & 15, hi = lane >> 4;
    int qbase = qt * 64;
    int qg = qbase + w * 16 + lo;
    bool uni = strict && (qg == 0);

    {
        int row = tid >> 2, d0 = (tid & 3) * 8;
        const float* p = Q + ((size_t)b * CS + qbase + row) * CE + h * 32 + d0;
        float4 a = *reinterpret_cast<const float4*>(p);
        float4 c = *reinterpret_cast<const float4*>(p + 4);
        unsigned short* dst = &Qs[row][d0];
        dst[0]=f2bf(a.x); dst[1]=f2bf(a.y); dst[2]=f2bf(a.z); dst[3]=f2bf(a.w);
        dst[4]=f2bf(c.x); dst[5]=f2bf(c.y); dst[6]=f2bf(c.z); dst[7]=f2bf(c.w);
    }
    __syncthreads();
    bf16x8 qfrag = *reinterpret_cast<const bf16x8*>(&Qs[w * 16 + lo][hi * 8]);

    f32x4 ctx0 = {0.f,0.f,0.f,0.f}, ctx1 = {0.f,0.f,0.f,0.f};
    float m = -1e30f, l = 0.f;

    int ntiles = (strict && qt == 0) ? (CS / 64) : (qt + 1);
    for (int t = 0; t < ntiles; ++t) {
        int k64 = t * 64;
        {
            int row = tid >> 2, d0 = (tid & 3) * 8;
            const float* kp = Q + ((size_t)b * CS + k64 + row) * CE + h * 32 + d0;
            float4 a = *reinterpret_cast<const float4*>(kp);
            float4 c = *reinterpret_cast<const float4*>(kp + 4);
            unsigned short* dst = &Ks[row][d0];
            dst[0]=f2bf(a.x); dst[1]=f2bf(a.y); dst[2]=f2bf(a.z); dst[3]=f2bf(a.w);
            dst[4]=f2bf(c.x); dst[5]=f2bf(c.y); dst[6]=f2bf(c.z); dst[7]=f2bf(c.w);
            const float* vp = V + ((size_t)b * CS + k64 + row) * CE + h * 32 + d0;
            float4 va = *reinterpret_cast<const float4*>(vp);
            float4 vc = *reinterpret_cast<const float4*>(vp + 4);
            VTs[d0+0][row]=f2bf(va.x); VTs[d0+1][row]=f2bf(va.y);
            VTs[d0+2][row]=f2bf(va.z); VTs[d0+3][row]=f2bf(va.w);
            VTs[d0+4][row]=f2bf(vc.x); VTs[d0+5][row]=f2bf(vc.y);
            VTs[d0+6][row]=f2bf(vc.z); VTs[d0+7][row]=f2bf(vc.w);
        }
        __syncthreads();

        f32x4 sacc[4];
#pragma unroll
        for (int kt = 0; kt < 4; ++kt) {
            bf16x8 kfrag = *reinterpret_cast<const bf16x8*>(&Ks[kt * 16 + lo][hi * 8]);
            f32x4 z = {0.f,0.f,0.f,0.f};
            sacc[kt] = __builtin_amdgcn_mfma_f32_16x16x32_bf16(kfrag, qfrag, z, 0, 0, 0);
        }
        float sv[16];
        float mt = -1e30f;
#pragma unroll
        for (int kt = 0; kt < 4; ++kt)
#pragma unroll
            for (int r = 0; r < 4; ++r) {
                int kidx = k64 + kt * 16 + hi * 4 + r;
                float s = sacc[kt][r] * SCALE;
                bool valid = strict ? (kidx < qg) : (kidx <= qg);
                s = valid ? s : -1e30f;
                if (uni) s = 0.f;
                sv[kt * 4 + r] = s;
                mt = fmaxf(mt, s);
            }
        mt = fmaxf(mt, __shfl_xor(mt, 16));
        mt = fmaxf(mt, __shfl_xor(mt, 32));
        float mn = fmaxf(m, mt);
        float co = __expf(m - mn);
        float lt = 0.f;
#pragma unroll
        for (int i = 0; i < 16; ++i) {
            float p = __expf(sv[i] - mn);
            sv[i] = p;
            lt += p;
        }
        lt += __shfl_xor(lt, 16);
        lt += __shfl_xor(lt, 32);
        l = l * co + lt;
        m = mn;
#pragma unroll
        for (int r = 0; r < 4; ++r) { ctx0[r] *= co; ctx1[r] *= co; }
#pragma unroll
        for (int kt = 0; kt < 4; ++kt) {
            unsigned short* pd = &Ps[w][lo][kt * 16 + hi * 4];
            pd[0] = f2bf(sv[kt * 4 + 0]); pd[1] = f2bf(sv[kt * 4 + 1]);
            pd[2] = f2bf(sv[kt * 4 + 2]); pd[3] = f2bf(sv[kt * 4 + 3]);
        }
        __syncthreads();
#pragma unroll
        for (int kh = 0; kh < 2; ++kh) {
            bf16x8 pfrag = *reinterpret_cast<const bf16x8*>(&Ps[w][lo][kh * 32 + hi * 8]);
            bf16x8 v0 = *reinterpret_cast<const bf16x8*>(&VTs[lo][kh * 32 + hi * 8]);
            bf16x8 v1 = *reinterpret_cast<const bf16x8*>(&VTs[16 + lo][kh * 32 + hi * 8]);
            ctx0 = __builtin_amdgcn_mfma_f32_16x16x32_bf16(v0, pfrag, ctx0, 0, 0, 0);
            ctx1 = __builtin_amdgcn_mfma_f32_16x16x32_bf16(v1, pfrag, ctx1, 0, 0, 0);
        }
        __syncthreads();
    }

    float inv = 1.f / l;
    float* cb = reinterpret_cast<float*>(&Ps[w][0][0]);   // [16 q][36 d]
#pragma unroll
    for (int r = 0; r < 4; ++r) {
        cb[lo * 36 + (hi * 4 + r)]      = ctx0[r] * inv;
        cb[lo * 36 + (16 + hi * 4 + r)] = ctx1[r] * inv;
    }
    __syncthreads();
    {
        int qloc = lane >> 2, d0 = (lane & 3) * 8;
        const float* src = cb + qloc * 36 + d0;
        float4 o0 = *reinterpret_cast<const float4*>(src);
        float4 o1 = *reinterpret_cast<const float4*>(src + 4);
        int i = qbase + w * 16 + qloc;
        float* op = Ctx + ((size_t)b * CS + i) * CE + h * 32 + d0;
        *reinterpret_cast<float4*>(op)     = o0;
        *reinterpret_cast<float4*>(op + 4) = o1;
    }
}

// ---------------------------------------------------------------- router gate
__global__ __launch_bounds__(64) void gate_kernel(
    const float* __restrict__ qin, const float* __restrict__ Wg,
    float* __restrict__ Ctx)
{
    int t = blockIdx.x;
    int lane = threadIdx.x;
    const float* q = qin + (size_t)t * CE;
    float p[CNDYN] = {};
#pragma unroll
    for (int r = 0; r < 4; ++r) {
        int e = lane + r * 64;
        float qe = q[e];
        const float* wg = &Wg[(size_t)e * CNDYN];
#pragma unroll
        for (int j = 0; j < CNDYN; ++j) p[j] += qe * wg[j];
    }
#pragma unroll
    for (int o = 32; o > 0; o >>= 1)
#pragma unroll
        for (int j = 0; j < CNDYN; ++j) p[j] += __shfl_down(p[j], o);
    int mask = 3;
    if (lane == 0) {
        for (int j = 0; j < CNDYN; ++j) {
            int rank = 0;
            for (int k = 0; k < CNDYN; ++k)
                if (p[k] > p[j] || (p[k] == p[j] && k < j)) rank++;
            if (rank < 4) mask |= 1 << (2 + j);
        }
    }
    mask = __shfl(mask, 0);
    float* c = Ctx + (size_t)t * CE;
#pragma unroll
    for (int r = 0; r < 4; ++r) {
        int e = lane + r * 64;
        int hh = e >> 5;
        if (!((mask >> hh) & 1)) c[e] = 0.f;
    }
}

// ---------------------------------------------------------------- residual+LN
__global__ __launch_bounds__(256) void add_ln(
    const float* __restrict__ A, const float* __restrict__ Bv,
    const float* __restrict__ g, const float* __restrict__ bb,
    float* __restrict__ O)
{
    __shared__ float red[8];
    int t = blockIdx.x, e = threadIdx.x;
    size_t base = (size_t)t * CE;
    float v = A[base + e] + Bv[base + e];
    float s = v;
#pragma unroll
    for (int o = 32; o > 0; o >>= 1) s += __shfl_down(s, o);
    int wid = e >> 6, lane = e & 63;
    if (lane == 0) red[wid] = s;
    __syncthreads();
    if (e == 0) red[4] = (red[0] + red[1] + red[2] + red[3]) * (1.f / CE);
    __syncthreads();
    float mean = red[4];
    float d = v - mean;
    float s2 = d * d;
#pragma unroll
    for (int o = 32; o > 0; o >>= 1) s2 += __shfl_down(s2, o);
    if (lane == 0) red[wid] = s2;
    __syncthreads();
    if (e == 0) red[5] = (red[0] + red[1] + red[2] + red[3]) * (1.f / CE);
    __syncthreads();
    float var = red[5];
    O[base + e] = d * rsqrtf(var + 1e-5f) * g[e] + bb[e];
}

// ---------------------------------------------------------------- concat
__global__ __launch_bounds__(256) void concat_kernel(
    const float* __restrict__ x, const float* __restrict__ qe,
    float* __restrict__ cat)
{
    int t = blockIdx.x, e = threadIdx.x;
    cat[(size_t)t * 512 + e]       = x[(size_t)t * CE + e];
    cat[(size_t)t * 512 + 256 + e] = qe[(size_t)t * CE + e];
}

// ---------------------------------------------------------------- final dot + sigmoid
__global__ __launch_bounds__(64) void final_kernel(
    const float* __restrict__ H2, const float* __restrict__ W3,
    const float* __restrict__ b3, float* __restrict__ out)
{
    int t = blockIdx.x, lane = threadIdx.x;
    const float* h = H2 + (size_t)t * CE;
    float s = 0.f;
#pragma unroll
    for (int r = 0; r < 4; ++r) {
        int e = lane + r * 64;
        s += h[e] * W3[e];
    }
#pragma unroll
    for (int o = 32; o > 0; o >>= 1) s += __shfl_down(s, o);
    if (lane == 0) {
        float v = 1.f / (1.f + __expf(-(s + b3[0])));
        int b = t >> 9, si = t & 511;
        if (si > 0) out[(size_t)b * (CS - 1) + si - 1] = v;
    }
}

// ---------------------------------------------------------------- driver
extern "C" void kernel_launch(void* const* d_in, const int* in_sizes, int n_in,
                              void* d_out, int out_size, void* d_ws, size_t ws_size,
                              hipStream_t stream)
{
    const int* skills    = (const int*)d_in[0];
    const int* responses = (const int*)d_in[1];
    const int* questions = (const int*)d_in[2];
    const float* q_embed       = (const float*)d_in[4];
    const float* qa_embed      = (const float*)d_in[5];
    const float* q_embed_diff  = (const float*)d_in[6];
    const float* qa_embed_diff = (const float*)d_in[7];
    const float* difficult     = (const float*)d_in[8];
    const float* Wq = (const float*)d_in[9];  const float* bq = (const float*)d_in[10];
    const float* Wv = (const float*)d_in[11]; const float* bv = (const float*)d_in[12];
    const float* Wo = (const float*)d_in[13]; const float* bo = (const float*)d_in[14];
    const float* Wg = (const float*)d_in[15];
    const float* ln1g = (const float*)d_in[16]; const float* ln1b = (const float*)d_in[17];
    const float* ln2g = (const float*)d_in[18]; const float* ln2b = (const float*)d_in[19];
    const float* fW1 = (const float*)d_in[20]; const float* fb1 = (const float*)d_in[21];
    const float* fW2 = (const float*)d_in[22]; const float* fb2 = (const float*)d_in[23];
    const float* oW1 = (const float*)d_in[24]; const float* ob1 = (const float*)d_in[25];
    const float* oW2 = (const float*)d_in[26]; const float* ob2 = (const float*)d_in[27];
    const float* oW3 = (const float*)d_in[28]; const float* ob3 = (const float*)d_in[29];
    float* out = (float*)d_out;

    char* ws = (char*)d_ws;
    const size_t R = (size_t)CT * CE * sizeof(float);   // 8 MB per region
    float* q_emb = (float*)(ws + 0 * R);
    float* xb    = (float*)(ws + 1 * R);
    float* yb    = (float*)(ws + 2 * R);
    float* S0    = (float*)(ws + 3 * R);   // S0..S1: cat buffer (16 MB)
    float* S1    = (float*)(ws + 4 * R);
    float* S2    = (float*)(ws + 5 * R);   // S2..S3: H1 buffer (16 MB)
    unsigned short* wT = (unsigned short*)(ws + 7 * R);  // bf16 transposed weights
    unsigned short* wqT = wT + (size_t)0  * 12 * 65536;
    unsigned short* wvT = wT + (size_t)1  * 12 * 65536;
    unsigned short* woT = wT + (size_t)2  * 12 * 65536;
    unsigned short* w1T = wT + (size_t)3  * 12 * 65536;
    unsigned short* w2T = wT + (size_t)4  * 12 * 65536;
    unsigned short* o1T = wT + (size_t)5  * 12 * 65536;          // [512][512]
    unsigned short* o2T = o1T + (size_t)512 * 512;               // [256][512]
    (void)in_sizes; (void)n_in; (void)out_size; (void)ws_size;

    // one-time weight conversion (runs every call; graph-safe)
    prep_w_layers<<<dim3(4, 4, 60), 256, 0, stream>>>(Wq, Wv, Wo, fW1, fW2, wT);
    prep_w_one<<<dim3(8, 8), 256, 0, stream>>>(oW1, o1T, 512, 512);
    prep_w_one<<<dim3(4, 8), 256, 0, stream>>>(oW2, o2T, 512, 256);

    embed_kernel<<<CT, 256, 0, stream>>>(skills, responses, questions,
        q_embed, qa_embed, q_embed_diff, qa_embed_diff, difficult, q_emb, yb);
    hipMemcpyAsync(xb, q_emb, R, hipMemcpyDeviceToDevice, stream);

    dim3 g256(4, 128);     // N=256 GEMMs

    auto layer = [&](int li, const float* qin, const float* vin, float* outc, int strict) {
        gemm_mfma<<<g256, 256, 0, stream>>>(qin, wqT + (size_t)li * 65536, bq + (size_t)li * CE, S0, CT, CE, CE, 0);
        gemm_mfma<<<g256, 256, 0, stream>>>(vin, wvT + (size_t)li * 65536, bv + (size_t)li * CE, S1, CT, CE, CE, 0);
        attn_mfma<<<CB * CH * 8, 256, 0, stream>>>(S0, S1, S2, strict);
        gate_kernel<<<CT, 64, 0, stream>>>(qin, Wg + (size_t)li * CE * CNDYN, S2);
        gemm_mfma<<<g256, 256, 0, stream>>>(S2, woT + (size_t)li * 65536, bo + (size_t)li * CE, S0, CT, CE, CE, 0);
        add_ln<<<CT, 256, 0, stream>>>(qin, S0, ln1g + (size_t)li * CE, ln1b + (size_t)li * CE, S1);
        gemm_mfma<<<g256, 256, 0, stream>>>(S1, w1T + (size_t)li * 65536, fb1 + (size_t)li * CE, S2, CT, CE, CE, 1);
        gemm_mfma<<<g256, 256, 0, stream>>>(S2, w2T + (size_t)li * 65536, fb2 + (size_t)li * CE, S0, CT, CE, CE, 0);
        add_ln<<<CT, 256, 0, stream>>>(S1, S0, ln2g + (size_t)li * CE, ln2b + (size_t)li * CE, outc);
    };

    for (int i = 0; i < 4; ++i) layer(i, yb, yb, yb, 0);
    int li = 4;
    for (int r = 0; r < 4; ++r) {
        layer(li, xb, xb, xb, 0); li++;
        layer(li, xb, yb, xb, 1); li++;   // q=x, k=x, v=y, strict mask
    }

    // output MLP
    concat_kernel<<<CT, 256, 0, stream>>>(xb, q_emb, S0);
    gemm_mfma<<<dim3(8, 128), 256, 0, stream>>>(S0, o1T, ob1, S2, CT, 512, 512, 1);
    gemm_mfma<<<dim3(4, 128), 256, 0, stream>>>(S2, o2T, ob2, xb, CT, 256, 512, 1);
    final_kernel<<<CT, 64, 0, stream>>>(xb, oW3, ob3, out);
}

// Round 8
// 1242.249 us; speedup vs baseline: 4.2489x; 1.1425x over previous
//
#include <hip/hip_runtime.h>
#include <hip/hip_bf16.h>

// Problem constants
constexpr int CB = 16, CS = 512, CE = 256, CH = 8, CDK = 32;
constexpr int CNDYN = 6;
constexpr int CT = CB * CS;          // 8192 tokens
constexpr float SCALE = 0.17677669529663687f; // 1/sqrt(32)

typedef __bf16 bf16x8 __attribute__((ext_vector_type(8)));
typedef float f32x4 __attribute__((ext_vector_type(4)));
typedef unsigned short u16x8 __attribute__((ext_vector_type(8)));

__device__ __forceinline__ unsigned short f2bf(float x) {
    union { float f; unsigned u; } v; v.f = x;
    unsigned r = v.u + 0x7fff + ((v.u >> 16) & 1);   // RNE
    return (unsigned short)(r >> 16);
}

// ---------------------------------------------------------------- embeddings
__global__ __launch_bounds__(256) void embed_kernel(
    const int* __restrict__ skills, const int* __restrict__ responses,
    const int* __restrict__ questions,
    const float* __restrict__ q_embed, const float* __restrict__ qa_embed,
    const float* __restrict__ q_embed_diff, const float* __restrict__ qa_embed_diff,
    const float* __restrict__ difficult,
    float* __restrict__ q_emb, float* __restrict__ qa_emb, float* __restrict__ xb)
{
    int t = blockIdx.x;
    int e = threadIdx.x;
    int sk = skills[t];
    int r  = responses[t];
    r = (r > -1) ? r : 0;            // masked_r
    float pid = difficult[questions[t]];
    float qe  = q_embed[(size_t)sk * CE + e];
    float qd  = q_embed_diff[(size_t)sk * CE + e];
    float qv  = qe + pid * qd;
    float qae = qe + qa_embed[(size_t)r * CE + e];
    float qad = qa_embed_diff[((size_t)sk + 1000 * r) * CE + e];
    float qav = qae + pid * (qad + qd);
    q_emb[(size_t)t * CE + e]  = qv;
    xb[(size_t)t * CE + e]     = qv;
    qa_emb[(size_t)t * CE + e] = qav;
}

// ---------------------------------------------------------------- weight prep
// Transpose+convert fp32 [K][N] -> bf16 [N][K].  Block 256, one 64x64 tile.
__device__ __forceinline__ void transpose_tile(
    const float* __restrict__ src, unsigned short* __restrict__ dst, int K, int N)
{
    __shared__ unsigned short T[64][72];
    int k0 = blockIdx.y * 64, n0 = blockIdx.x * 64;
    int t = threadIdx.x;
    int kr = t >> 3, nsg = (t & 7) * 8;
#pragma unroll
    for (int rr = 0; rr < 64; rr += 32) {
        const float* p = src + (size_t)(k0 + kr + rr) * N + n0 + nsg;
        float4 a = *reinterpret_cast<const float4*>(p);
        float4 b = *reinterpret_cast<const float4*>(p + 4);
        int k = kr + rr;
        T[nsg + 0][k] = f2bf(a.x); T[nsg + 1][k] = f2bf(a.y);
        T[nsg + 2][k] = f2bf(a.z); T[nsg + 3][k] = f2bf(a.w);
        T[nsg + 4][k] = f2bf(b.x); T[nsg + 5][k] = f2bf(b.y);
        T[nsg + 6][k] = f2bf(b.z); T[nsg + 7][k] = f2bf(b.w);
    }
    __syncthreads();
    {
        int n = t >> 2, ks = (t & 3) * 16;
        unsigned short* dp = dst + (size_t)(n0 + n) * K + k0 + ks;
        *reinterpret_cast<u16x8*>(dp)     = *reinterpret_cast<const u16x8*>(&T[n][ks]);
        *reinterpret_cast<u16x8*>(dp + 8) = *reinterpret_cast<const u16x8*>(&T[n][ks + 8]);
    }
}

// grid (4,4,60): z -> {Wq,Wv,Wo,fW1,fW2}[z/12], layer z%12 (256x256 each).
// Wq/Wv interleave per layer into qvT: [layer][512 rows][256 k].
__global__ __launch_bounds__(256) void prep_w_layers(
    const float* __restrict__ Wq, const float* __restrict__ Wv,
    const float* __restrict__ Wo, const float* __restrict__ W1,
    const float* __restrict__ W2,
    unsigned short* __restrict__ qvT, unsigned short* __restrict__ woT,
    unsigned short* __restrict__ w1T, unsigned short* __restrict__ w2T)
{
    int z = blockIdx.z;
    int which = z / 12, l = z % 12;
    const float* src;
    unsigned short* dst;
    if      (which == 0) { src = Wq + (size_t)l * 65536; dst = qvT + (size_t)l * 131072; }
    else if (which == 1) { src = Wv + (size_t)l * 65536; dst = qvT + (size_t)l * 131072 + 65536; }
    else if (which == 2) { src = Wo + (size_t)l * 65536; dst = woT + (size_t)l * 65536; }
    else if (which == 3) { src = W1 + (size_t)l * 65536; dst = w1T + (size_t)l * 65536; }
    else                 { src = W2 + (size_t)l * 65536; dst = w2T + (size_t)l * 65536; }
    transpose_tile(src, dst, 256, 256);
}

__global__ __launch_bounds__(256) void prep_w_one(
    const float* __restrict__ src, unsigned short* __restrict__ dst, int K, int N)
{
    transpose_tile(src, dst, K, N);
}

// ---------------------------------------------------------------- MFMA GEMM
// C = A[M,K](fp32) @ W + bias; W as WT[N][K] bf16. 64x64 tile, BK=64, 4 waves.
// split>0: cols >= split go to C2 (+bias2), both halves row-stride = split/N-split.
// gmask: per-row 8-bit head mask applied to A during staging (Wo gate fusion).
__global__ __launch_bounds__(256) void gemm_mfma(
    const float* __restrict__ A, const unsigned short* __restrict__ WT,
    const float* __restrict__ bias, float* __restrict__ C,
    const float* __restrict__ bias2, float* __restrict__ C2,
    const unsigned char* __restrict__ gmask,
    int M, int N, int K, int relu, int split)
{
    __shared__ __attribute__((aligned(16))) unsigned short As[64][72];
    __shared__ __attribute__((aligned(16))) unsigned short Bs[64][72];
    int tid = threadIdx.x;
    int bm = blockIdx.y * 64, bn = blockIdx.x * 64;
    int w = tid >> 6, lane = tid & 63;
    int wr = w >> 1, wc = w & 1;
    int lo = lane & 15, hi = lane >> 4;
    int srow = tid >> 2, sseg = (tid & 3) * 16;
    f32x4 acc[2][2] = {};

    for (int kk = 0; kk < K; kk += 64) {
        {   // A: 64 rows x 64 k, fp32 -> bf16 (optional gate mask)
            const float* ap = A + (size_t)(bm + srow) * K + kk + sseg;
            float4 a0 = *reinterpret_cast<const float4*>(ap);
            float4 a1 = *reinterpret_cast<const float4*>(ap + 4);
            float4 a2 = *reinterpret_cast<const float4*>(ap + 8);
            float4 a3 = *reinterpret_cast<const float4*>(ap + 12);
            if (gmask) {   // 16-col chunk never crosses a 32-col head boundary
                int hh = (kk + sseg) >> 5;
                float km = ((gmask[bm + srow] >> hh) & 1) ? 1.f : 0.f;
                a0.x*=km; a0.y*=km; a0.z*=km; a0.w*=km;
                a1.x*=km; a1.y*=km; a1.z*=km; a1.w*=km;
                a2.x*=km; a2.y*=km; a2.z*=km; a2.w*=km;
                a3.x*=km; a3.y*=km; a3.z*=km; a3.w*=km;
            }
            u16x8 p0, p1;
            p0[0]=f2bf(a0.x); p0[1]=f2bf(a0.y); p0[2]=f2bf(a0.z); p0[3]=f2bf(a0.w);
            p0[4]=f2bf(a1.x); p0[5]=f2bf(a1.y); p0[6]=f2bf(a1.z); p0[7]=f2bf(a1.w);
            p1[0]=f2bf(a2.x); p1[1]=f2bf(a2.y); p1[2]=f2bf(a2.z); p1[3]=f2bf(a2.w);
            p1[4]=f2bf(a3.x); p1[5]=f2bf(a3.y); p1[6]=f2bf(a3.z); p1[7]=f2bf(a3.w);
            *reinterpret_cast<u16x8*>(&As[srow][sseg])     = p0;
            *reinterpret_cast<u16x8*>(&As[srow][sseg + 8]) = p1;
            // B: 64 n-rows x 64 k from bf16 WT
            const unsigned short* bp = WT + (size_t)(bn + srow) * K + kk + sseg;
            *reinterpret_cast<u16x8*>(&Bs[srow][sseg])     = *reinterpret_cast<const u16x8*>(bp);
            *reinterpret_cast<u16x8*>(&Bs[srow][sseg + 8]) = *reinterpret_cast<const u16x8*>(bp + 8);
        }
        __syncthreads();
#pragma unroll
        for (int ks = 0; ks < 2; ++ks) {
            bf16x8 a0 = *reinterpret_cast<const bf16x8*>(&As[wr * 32 + lo][ks * 32 + hi * 8]);
            bf16x8 a1 = *reinterpret_cast<const bf16x8*>(&As[wr * 32 + 16 + lo][ks * 32 + hi * 8]);
            bf16x8 b0 = *reinterpret_cast<const bf16x8*>(&Bs[wc * 32 + lo][ks * 32 + hi * 8]);
            bf16x8 b1 = *reinterpret_cast<const bf16x8*>(&Bs[wc * 32 + 16 + lo][ks * 32 + hi * 8]);
            acc[0][0] = __builtin_amdgcn_mfma_f32_16x16x32_bf16(a0, b0, acc[0][0], 0, 0, 0);
            acc[0][1] = __builtin_amdgcn_mfma_f32_16x16x32_bf16(a0, b1, acc[0][1], 0, 0, 0);
            acc[1][0] = __builtin_amdgcn_mfma_f32_16x16x32_bf16(a1, b0, acc[1][0], 0, 0, 0);
            acc[1][1] = __builtin_amdgcn_mfma_f32_16x16x32_bf16(a1, b1, acc[1][1], 0, 0, 0);
        }
        __syncthreads();
    }
    const float* bp = bias;
    float* Cp = C;
    int ldc = split ? split : N;
    int cb = bn;
    if (split && bn >= split) { bp = bias2; Cp = C2; ldc = N - split; cb = bn - split; }
#pragma unroll
    for (int i = 0; i < 2; ++i)
#pragma unroll
        for (int j = 0; j < 2; ++j) {
            int col = cb + wc * 32 + j * 16 + lo;
            float bv = bp[col];
#pragma unroll
            for (int r = 0; r < 4; ++r) {
                int row = bm + wr * 32 + i * 16 + hi * 4 + r;
                float v = acc[i][j][r] + bv;
                if (relu) v = fmaxf(v, 0.f);
                Cp[(size_t)row * ldc + col] = v;
            }
        }
}

// ---------------------------------------------------------------- attention (bf16 MFMA flash)
__global__ __launch_bounds__(256) void attn_mfma(
    const float* __restrict__ Q, const float* __restrict__ V,
    float* __restrict__ Ctx, int strict)
{
    __shared__ __attribute__((aligned(16))) unsigned short Qs[64][40];
    __shared__ __attribute__((aligned(16))) unsigned short Ks[64][40];
    __shared__ __attribute__((aligned(16))) unsigned short VTs[32][72];
    __shared__ __attribute__((aligned(16))) unsigned short Ps[4][16][72]; // per-wave; reused as f32 ctxbuf[16][36]

    int blk = blockIdx.x;
    int qt = blk & 7;
    int h  = (blk >> 3) & 7;
    int b  = blk >> 6;
    int tid = threadIdx.x;
    int w = tid >> 6, lane = tid & 63;
    int lo = lane & 15, hi = lane >> 4;
    int qbase = qt * 64;
    int qg = qbase + w * 16 + lo;
    bool uni = strict && (qg == 0);

    {
        int row = tid >> 2, d0 = (tid & 3) * 8;
        const float* p = Q + ((size_t)b * CS + qbase + row) * CE + h * 32 + d0;
        float4 a = *reinterpret_cast<const float4*>(p);
        float4 c = *reinterpret_cast<const float4*>(p + 4);
        unsigned short* dst = &Qs[row][d0];
        dst[0]=f2bf(a.x); dst[1]=f2bf(a.y); dst[2]=f2bf(a.z); dst[3]=f2bf(a.w);
        dst[4]=f2bf(c.x); dst[5]=f2bf(c.y); dst[6]=f2bf(c.z); dst[7]=f2bf(c.w);
    }
    __syncthreads();
    bf16x8 qfrag = *reinterpret_cast<const bf16x8*>(&Qs[w * 16 + lo][hi * 8]);

    f32x4 ctx0 = {0.f,0.f,0.f,0.f}, ctx1 = {0.f,0.f,0.f,0.f};
    float m = -1e30f, l = 0.f;

    int ntiles = (strict && qt == 0) ? (CS / 64) : (qt + 1);
    for (int t = 0; t < ntiles; ++t) {
        int k64 = t * 64;
        {
            int row = tid >> 2, d0 = (tid & 3) * 8;
            const float* kp = Q + ((size_t)b * CS + k64 + row) * CE + h * 32 + d0;
            float4 a = *reinterpret_cast<const float4*>(kp);
            float4 c = *reinterpret_cast<const float4*>(kp + 4);
            unsigned short* dst = &Ks[row][d0];
            dst[0]=f2bf(a.x); dst[1]=f2bf(a.y); dst[2]=f2bf(a.z); dst[3]=f2bf(a.w);
            dst[4]=f2bf(c.x); dst[5]=f2bf(c.y); dst[6]=f2bf(c.z); dst[7]=f2bf(c.w);
            const float* vp = V + ((size_t)b * CS + k64 + row) * CE + h * 32 + d0;
            float4 va = *reinterpret_cast<const float4*>(vp);
            float4 vc = *reinterpret_cast<const float4*>(vp + 4);
            VTs[d0+0][row]=f2bf(va.x); VTs[d0+1][row]=f2bf(va.y);
            VTs[d0+2][row]=f2bf(va.z); VTs[d0+3][row]=f2bf(va.w);
            VTs[d0+4][row]=f2bf(vc.x); VTs[d0+5][row]=f2bf(vc.y);
            VTs[d0+6][row]=f2bf(vc.z); VTs[d0+7][row]=f2bf(vc.w);
        }
        __syncthreads();

        f32x4 sacc[4];
#pragma unroll
        for (int kt = 0; kt < 4; ++kt) {
            bf16x8 kfrag = *reinterpret_cast<const bf16x8*>(&Ks[kt * 16 + lo][hi * 8]);
            f32x4 z = {0.f,0.f,0.f,0.f};
            sacc[kt] = __builtin_amdgcn_mfma_f32_16x16x32_bf16(kfrag, qfrag, z, 0, 0, 0);
        }
        float sv[16];
        float mt = -1e30f;
#pragma unroll
        for (int kt = 0; kt < 4; ++kt)
#pragma unroll
            for (int r = 0; r < 4; ++r) {
                int kidx = k64 + kt * 16 + hi * 4 + r;
                float s = sacc[kt][r] * SCALE;
                bool valid = strict ? (kidx < qg) : (kidx <= qg);
                s = valid ? s : -1e30f;
                if (uni) s = 0.f;
                sv[kt * 4 + r] = s;
                mt = fmaxf(mt, s);
            }
        mt = fmaxf(mt, __shfl_xor(mt, 16));
        mt = fmaxf(mt, __shfl_xor(mt, 32));
        float mn = fmaxf(m, mt);
        float co = __expf(m - mn);
        float lt = 0.f;
#pragma unroll
        for (int i = 0; i < 16; ++i) {
            float p = __expf(sv[i] - mn);
            sv[i] = p;
            lt += p;
        }
        lt += __shfl_xor(lt, 16);
        lt += __shfl_xor(lt, 32);
        l = l * co + lt;
        m = mn;
#pragma unroll
        for (int r = 0; r < 4; ++r) { ctx0[r] *= co; ctx1[r] *= co; }
#pragma unroll
        for (int kt = 0; kt < 4; ++kt) {
            unsigned short* pd = &Ps[w][lo][kt * 16 + hi * 4];
            pd[0] = f2bf(sv[kt * 4 + 0]); pd[1] = f2bf(sv[kt * 4 + 1]);
            pd[2] = f2bf(sv[kt * 4 + 2]); pd[3] = f2bf(sv[kt * 4 + 3]);
        }
        __syncthreads();
#pragma unroll
        for (int kh = 0; kh < 2; ++kh) {
            bf16x8 pfrag = *reinterpret_cast<const bf16x8*>(&Ps[w][lo][kh * 32 + hi * 8]);
            bf16x8 v0 = *reinterpret_cast<const bf16x8*>(&VTs[lo][kh * 32 + hi * 8]);
            bf16x8 v1 = *reinterpret_cast<const bf16x8*>(&VTs[16 + lo][kh * 32 + hi * 8]);
            ctx0 = __builtin_amdgcn_mfma_f32_16x16x32_bf16(v0, pfrag, ctx0, 0, 0, 0);
            ctx1 = __builtin_amdgcn_mfma_f32_16x16x32_bf16(v1, pfrag, ctx1, 0, 0, 0);
        }
        __syncthreads();
    }

    float inv = 1.f / l;
    float* cb = reinterpret_cast<float*>(&Ps[w][0][0]);   // [16 q][36 d]
#pragma unroll
    for (int r = 0; r < 4; ++r) {
        cb[lo * 36 + (hi * 4 + r)]      = ctx0[r] * inv;
        cb[lo * 36 + (16 + hi * 4 + r)] = ctx1[r] * inv;
    }
    __syncthreads();
    {
        int qloc = lane >> 2, d0 = (lane & 3) * 8;
        const float* src = cb + qloc * 36 + d0;
        float4 o0 = *reinterpret_cast<const float4*>(src);
        float4 o1 = *reinterpret_cast<const float4*>(src + 4);
        int i = qbase + w * 16 + qloc;
        float* op = Ctx + ((size_t)b * CS + i) * CE + h * 32 + d0;
        *reinterpret_cast<float4*>(op)     = o0;
        *reinterpret_cast<float4*>(op + 4) = o1;
    }
}

// ---------------------------------------------------------------- router gate mask
// logits = q_in @ Wg (E x 6); top-4 (stable ties) -> 8-bit head mask (heads 0,1 shared).
__global__ __launch_bounds__(64) void gate_mask(
    const float* __restrict__ qin, const float* __restrict__ Wg,
    unsigned char* __restrict__ mb)
{
    int t = blockIdx.x;
    int lane = threadIdx.x;
    const float* q = qin + (size_t)t * CE;
    float p[CNDYN] = {};
#pragma unroll
    for (int r = 0; r < 4; ++r) {
        int e = lane + r * 64;
        float qe = q[e];
        const float* wg = &Wg[(size_t)e * CNDYN];
#pragma unroll
        for (int j = 0; j < CNDYN; ++j) p[j] += qe * wg[j];
    }
#pragma unroll
    for (int o = 32; o > 0; o >>= 1)
#pragma unroll
        for (int j = 0; j < CNDYN; ++j) p[j] += __shfl_down(p[j], o);
    if (lane == 0) {
        int mask = 3;
        for (int j = 0; j < CNDYN; ++j) {
            int rank = 0;
            for (int k = 0; k < CNDYN; ++k)
                if (p[k] > p[j] || (p[k] == p[j] && k < j)) rank++;
            if (rank < 4) mask |= 1 << (2 + j);
        }
        mb[t] = (unsigned char)mask;
    }
}

// ---------------------------------------------------------------- residual+LN
// 4 waves/block, wave = one token, lane holds float4 (16B/lane).
__global__ __launch_bounds__(256) void add_ln(
    const float* __restrict__ A, const float* __restrict__ Bv,
    const float* __restrict__ g, const float* __restrict__ bb,
    float* __restrict__ O)
{
    int w = threadIdx.x >> 6, lane = threadIdx.x & 63;
    int t = blockIdx.x * 4 + w;
    size_t base = (size_t)t * CE + lane * 4;
    float4 a = *reinterpret_cast<const float4*>(A + base);
    float4 b = *reinterpret_cast<const float4*>(Bv + base);
    float4 v = {a.x + b.x, a.y + b.y, a.z + b.z, a.w + b.w};
    float s = v.x + v.y + v.z + v.w;
#pragma unroll
    for (int o = 32; o > 0; o >>= 1) s += __shfl_xor(s, o);
    float mean = s * (1.f / CE);
    float4 d = {v.x - mean, v.y - mean, v.z - mean, v.w - mean};
    float s2 = d.x * d.x + d.y * d.y + d.z * d.z + d.w * d.w;
#pragma unroll
    for (int o = 32; o > 0; o >>= 1) s2 += __shfl_xor(s2, o);
    float rstd = rsqrtf(s2 * (1.f / CE) + 1e-5f);
    float4 gg = *reinterpret_cast<const float4*>(g + lane * 4);
    float4 bv4 = *reinterpret_cast<const float4*>(bb + lane * 4);
    float4 o4 = {d.x * rstd * gg.x + bv4.x, d.y * rstd * gg.y + bv4.y,
                 d.z * rstd * gg.z + bv4.z, d.w * rstd * gg.w + bv4.w};
    *reinterpret_cast<float4*>(O + base) = o4;
}

// ---------------------------------------------------------------- concat
__global__ __launch_bounds__(256) void concat_kernel(
    const float* __restrict__ x, const float* __restrict__ qe,
    float* __restrict__ cat)
{
    int t = blockIdx.x, e = threadIdx.x;
    cat[(size_t)t * 512 + e]       = x[(size_t)t * CE + e];
    cat[(size_t)t * 512 + 256 + e] = qe[(size_t)t * CE + e];
}

// ---------------------------------------------------------------- final dot + sigmoid
__global__ __launch_bounds__(64) void final_kernel(
    const float* __restrict__ H2, const float* __restrict__ W3,
    const float* __restrict__ b3, float* __restrict__ out)
{
    int t = blockIdx.x, lane = threadIdx.x;
    const float* h = H2 + (size_t)t * CE;
    float s = 0.f;
#pragma unroll
    for (int r = 0; r < 4; ++r) {
        int e = lane + r * 64;
        s += h[e] * W3[e];
    }
#pragma unroll
    for (int o = 32; o > 0; o >>= 1) s += __shfl_down(s, o);
    if (lane == 0) {
        float v = 1.f / (1.f + __expf(-(s + b3[0])));
        int b = t >> 9, si = t & 511;
        if (si > 0) out[(size_t)b * (CS - 1) + si - 1] = v;
    }
}

// ---------------------------------------------------------------- driver
extern "C" void kernel_launch(void* const* d_in, const int* in_sizes, int n_in,
                              void* d_out, int out_size, void* d_ws, size_t ws_size,
                              hipStream_t stream)
{
    const int* skills    = (const int*)d_in[0];
    const int* responses = (const int*)d_in[1];
    const int* questions = (const int*)d_in[2];
    const float* q_embed       = (const float*)d_in[4];
    const float* qa_embed      = (const float*)d_in[5];
    const float* q_embed_diff  = (const float*)d_in[6];
    const float* qa_embed_diff = (const float*)d_in[7];
    const float* difficult     = (const float*)d_in[8];
    const float* Wq = (const float*)d_in[9];  const float* bq = (const float*)d_in[10];
    const float* Wv = (const float*)d_in[11]; const float* bv = (const float*)d_in[12];
    const float* Wo = (const float*)d_in[13]; const float* bo = (const float*)d_in[14];
    const float* Wg = (const float*)d_in[15];
    const float* ln1g = (const float*)d_in[16]; const float* ln1b = (const float*)d_in[17];
    const float* ln2g = (const float*)d_in[18]; const float* ln2b = (const float*)d_in[19];
    const float* fW1 = (const float*)d_in[20]; const float* fb1 = (const float*)d_in[21];
    const float* fW2 = (const float*)d_in[22]; const float* fb2 = (const float*)d_in[23];
    const float* oW1 = (const float*)d_in[24]; const float* ob1 = (const float*)d_in[25];
    const float* oW2 = (const float*)d_in[26]; const float* ob2 = (const float*)d_in[27];
    const float* oW3 = (const float*)d_in[28]; const float* ob3 = (const float*)d_in[29];
    float* out = (float*)d_out;

    char* ws = (char*)d_ws;
    const size_t R = (size_t)CT * CE * sizeof(float);   // 8 MB per region
    float* q_emb = (float*)(ws + 0 * R);
    float* xb    = (float*)(ws + 1 * R);
    float* yb    = (float*)(ws + 2 * R);
    float* S0    = (float*)(ws + 3 * R);   // S0..S1: 16MB cat buffer
    float* S1    = (float*)(ws + 4 * R);
    float* S2    = (float*)(ws + 5 * R);   // S2..S3: 16MB H1 buffer
    unsigned short* qvT = (unsigned short*)(ws + 7 * R);  // [12][512][256]
    unsigned short* woT = qvT + (size_t)12 * 131072;      // [12][256][256]
    unsigned short* w1T = woT + (size_t)12 * 65536;
    unsigned short* w2T = w1T + (size_t)12 * 65536;
    unsigned short* o1T = w2T + (size_t)12 * 65536;       // [512][512]
    unsigned short* o2T = o1T + (size_t)512 * 512;        // [256][512]
    unsigned char* maskbuf = (unsigned char*)(o2T + (size_t)256 * 512);
    (void)in_sizes; (void)n_in; (void)out_size; (void)ws_size;

    // weight conversion (every call; graph-safe)
    prep_w_layers<<<dim3(4, 4, 60), 256, 0, stream>>>(Wq, Wv, Wo, fW1, fW2, qvT, woT, w1T, w2T);
    prep_w_one<<<dim3(8, 8), 256, 0, stream>>>(oW1, o1T, 512, 512);
    prep_w_one<<<dim3(4, 8), 256, 0, stream>>>(oW2, o2T, 512, 256);

    embed_kernel<<<CT, 256, 0, stream>>>(skills, responses, questions,
        q_embed, qa_embed, q_embed_diff, qa_embed_diff, difficult, q_emb, yb, xb);

    auto layer = [&](int li, const float* qin, const float* vin, float* outc, int strict) {
        if (qin == vin) {   // fused Q+V projection (N=512, split at 256)
            gemm_mfma<<<dim3(8, 128), 256, 0, stream>>>(qin, qvT + (size_t)li * 131072,
                bq + (size_t)li * CE, S0, bv + (size_t)li * CE, S1, nullptr,
                CT, 512, CE, 0, 256);
        } else {
            gemm_mfma<<<dim3(4, 128), 256, 0, stream>>>(qin, qvT + (size_t)li * 131072,
                bq + (size_t)li * CE, S0, nullptr, nullptr, nullptr, CT, CE, CE, 0, 0);
            gemm_mfma<<<dim3(4, 128), 256, 0, stream>>>(vin, qvT + (size_t)li * 131072 + 65536,
                bv + (size_t)li * CE, S1, nullptr, nullptr, nullptr, CT, CE, CE, 0, 0);
        }
        gate_mask<<<CT, 64, 0, stream>>>(qin, Wg + (size_t)li * CE * CNDYN, maskbuf);
        attn_mfma<<<CB * CH * 8, 256, 0, stream>>>(S0, S1, S2, strict);
        gemm_mfma<<<dim3(4, 128), 256, 0, stream>>>(S2, woT + (size_t)li * 65536,
            bo + (size_t)li * CE, S0, nullptr, nullptr, maskbuf, CT, CE, CE, 0, 0);
        add_ln<<<CT / 4, 256, 0, stream>>>(qin, S0, ln1g + (size_t)li * CE, ln1b + (size_t)li * CE, S1);
        gemm_mfma<<<dim3(4, 128), 256, 0, stream>>>(S1, w1T + (size_t)li * 65536,
            fb1 + (size_t)li * CE, S2, nullptr, nullptr, nullptr, CT, CE, CE, 1, 0);
        gemm_mfma<<<dim3(4, 128), 256, 0, stream>>>(S2, w2T + (size_t)li * 65536,
            fb2 + (size_t)li * CE, S0, nullptr, nullptr, nullptr, CT, CE, CE, 0, 0);
        add_ln<<<CT / 4, 256, 0, stream>>>(S1, S0, ln2g + (size_t)li * CE, ln2b + (size_t)li * CE, outc);
    };

    for (int i = 0; i < 4; ++i) layer(i, yb, yb, yb, 0);
    int li = 4;
    for (int r = 0; r < 4; ++r) {
        layer(li, xb, xb, xb, 0); li++;
        layer(li, xb, yb, xb, 1); li++;   // q=x, k=x, v=y, strict mask
    }

    // output MLP
    concat_kernel<<<CT, 256, 0, stream>>>(xb, q_emb, S0);
    gemm_mfma<<<dim3(8, 128), 256, 0, stream>>>(S0, o1T, ob1, S2, nullptr, nullptr, nullptr, CT, 512, 512, 1, 0);
    gemm_mfma<<<dim3(4, 128), 256, 0, stream>>>(S2, o2T, ob2, xb, nullptr, nullptr, nullptr, CT, 256, 512, 1, 0);
    final_kernel<<<CT, 64, 0, stream>>>(xb, oW3, ob3, out);
}

// Round 9
// 1161.233 us; speedup vs baseline: 4.5453x; 1.0698x over previous
//
#include <hip/hip_runtime.h>
#include <hip/hip_bf16.h>

// Problem constants
constexpr int CB = 16, CS = 512, CE = 256, CH = 8, CDK = 32;
constexpr int CNDYN = 6;
constexpr int CT = CB * CS;          // 8192 tokens
constexpr float SCALE = 0.17677669529663687f; // 1/sqrt(32)

typedef __bf16 bf16x8 __attribute__((ext_vector_type(8)));
typedef float f32x4 __attribute__((ext_vector_type(4)));
typedef unsigned short u16x8 __attribute__((ext_vector_type(8)));

__device__ __forceinline__ unsigned short f2bf(float x) {
    union { float f; unsigned u; } v; v.f = x;
    unsigned r = v.u + 0x7fff + ((v.u >> 16) & 1);   // RNE
    return (unsigned short)(r >> 16);
}

// ---------------------------------------------------------------- embeddings
__global__ __launch_bounds__(256) void embed_kernel(
    const int* __restrict__ skills, const int* __restrict__ responses,
    const int* __restrict__ questions,
    const float* __restrict__ q_embed, const float* __restrict__ qa_embed,
    const float* __restrict__ q_embed_diff, const float* __restrict__ qa_embed_diff,
    const float* __restrict__ difficult,
    float* __restrict__ q_emb, float* __restrict__ qa_emb, float* __restrict__ xb)
{
    int t = blockIdx.x;
    int e = threadIdx.x;
    int sk = skills[t];
    int r  = responses[t];
    r = (r > -1) ? r : 0;            // masked_r
    float pid = difficult[questions[t]];
    float qe  = q_embed[(size_t)sk * CE + e];
    float qd  = q_embed_diff[(size_t)sk * CE + e];
    float qv  = qe + pid * qd;
    float qae = qe + qa_embed[(size_t)r * CE + e];
    float qad = qa_embed_diff[((size_t)sk + 1000 * r) * CE + e];
    float qav = qae + pid * (qad + qd);
    q_emb[(size_t)t * CE + e]  = qv;
    xb[(size_t)t * CE + e]     = qv;
    qa_emb[(size_t)t * CE + e] = qav;
}

// ---------------------------------------------------------------- weight prep
__device__ __forceinline__ void transpose_tile(
    const float* __restrict__ src, unsigned short* __restrict__ dst, int K, int N)
{
    __shared__ unsigned short T[64][72];
    int k0 = blockIdx.y * 64, n0 = blockIdx.x * 64;
    int t = threadIdx.x;
    int kr = t >> 3, nsg = (t & 7) * 8;
#pragma unroll
    for (int rr = 0; rr < 64; rr += 32) {
        const float* p = src + (size_t)(k0 + kr + rr) * N + n0 + nsg;
        float4 a = *reinterpret_cast<const float4*>(p);
        float4 b = *reinterpret_cast<const float4*>(p + 4);
        int k = kr + rr;
        T[nsg + 0][k] = f2bf(a.x); T[nsg + 1][k] = f2bf(a.y);
        T[nsg + 2][k] = f2bf(a.z); T[nsg + 3][k] = f2bf(a.w);
        T[nsg + 4][k] = f2bf(b.x); T[nsg + 5][k] = f2bf(b.y);
        T[nsg + 6][k] = f2bf(b.z); T[nsg + 7][k] = f2bf(b.w);
    }
    __syncthreads();
    {
        int n = t >> 2, ks = (t & 3) * 16;
        unsigned short* dp = dst + (size_t)(n0 + n) * K + k0 + ks;
        *reinterpret_cast<u16x8*>(dp)     = *reinterpret_cast<const u16x8*>(&T[n][ks]);
        *reinterpret_cast<u16x8*>(dp + 8) = *reinterpret_cast<const u16x8*>(&T[n][ks + 8]);
    }
}

// grid (4,4,60): z -> {Wq,Wv,Wo,fW1,fW2}[z/12], layer z%12 (256x256 each).
__global__ __launch_bounds__(256) void prep_w_layers(
    const float* __restrict__ Wq, const float* __restrict__ Wv,
    const float* __restrict__ Wo, const float* __restrict__ W1,
    const float* __restrict__ W2,
    unsigned short* __restrict__ qvT, unsigned short* __restrict__ woT,
    unsigned short* __restrict__ w1T, unsigned short* __restrict__ w2T)
{
    int z = blockIdx.z;
    int which = z / 12, l = z % 12;
    const float* src;
    unsigned short* dst;
    if      (which == 0) { src = Wq + (size_t)l * 65536; dst = qvT + (size_t)l * 131072; }
    else if (which == 1) { src = Wv + (size_t)l * 65536; dst = qvT + (size_t)l * 131072 + 65536; }
    else if (which == 2) { src = Wo + (size_t)l * 65536; dst = woT + (size_t)l * 65536; }
    else if (which == 3) { src = W1 + (size_t)l * 65536; dst = w1T + (size_t)l * 65536; }
    else                 { src = W2 + (size_t)l * 65536; dst = w2T + (size_t)l * 65536; }
    transpose_tile(src, dst, 256, 256);
}

__global__ __launch_bounds__(256) void prep_w_one(
    const float* __restrict__ src, unsigned short* __restrict__ dst, int K, int N)
{
    transpose_tile(src, dst, K, N);
}

// ---------------------------------------------------------------- MFMA GEMM
// C = A[M,K](fp32) @ W + bias; W as WT[N][K] bf16. 64x64 tile, BK=64, 4 waves.
// split>0: cols >= split go to C2 (+bias2). gmask: per-row head mask on A (Wo fusion).
__global__ __launch_bounds__(256) void gemm_mfma(
    const float* __restrict__ A, const unsigned short* __restrict__ WT,
    const float* __restrict__ bias, float* __restrict__ C,
    const float* __restrict__ bias2, float* __restrict__ C2,
    const unsigned char* __restrict__ gmask,
    int M, int N, int K, int relu, int split)
{
    __shared__ __attribute__((aligned(16))) unsigned short As[64][72];
    __shared__ __attribute__((aligned(16))) unsigned short Bs[64][72];
    int tid = threadIdx.x;
    int bm = blockIdx.y * 64, bn = blockIdx.x * 64;
    int w = tid >> 6, lane = tid & 63;
    int wr = w >> 1, wc = w & 1;
    int lo = lane & 15, hi = lane >> 4;
    int srow = tid >> 2, sseg = (tid & 3) * 16;
    f32x4 acc[2][2] = {};

    for (int kk = 0; kk < K; kk += 64) {
        {
            const float* ap = A + (size_t)(bm + srow) * K + kk + sseg;
            float4 a0 = *reinterpret_cast<const float4*>(ap);
            float4 a1 = *reinterpret_cast<const float4*>(ap + 4);
            float4 a2 = *reinterpret_cast<const float4*>(ap + 8);
            float4 a3 = *reinterpret_cast<const float4*>(ap + 12);
            if (gmask) {
                int hh = (kk + sseg) >> 5;
                float km = ((gmask[bm + srow] >> hh) & 1) ? 1.f : 0.f;
                a0.x*=km; a0.y*=km; a0.z*=km; a0.w*=km;
                a1.x*=km; a1.y*=km; a1.z*=km; a1.w*=km;
                a2.x*=km; a2.y*=km; a2.z*=km; a2.w*=km;
                a3.x*=km; a3.y*=km; a3.z*=km; a3.w*=km;
            }
            u16x8 p0, p1;
            p0[0]=f2bf(a0.x); p0[1]=f2bf(a0.y); p0[2]=f2bf(a0.z); p0[3]=f2bf(a0.w);
            p0[4]=f2bf(a1.x); p0[5]=f2bf(a1.y); p0[6]=f2bf(a1.z); p0[7]=f2bf(a1.w);
            p1[0]=f2bf(a2.x); p1[1]=f2bf(a2.y); p1[2]=f2bf(a2.z); p1[3]=f2bf(a2.w);
            p1[4]=f2bf(a3.x); p1[5]=f2bf(a3.y); p1[6]=f2bf(a3.z); p1[7]=f2bf(a3.w);
            *reinterpret_cast<u16x8*>(&As[srow][sseg])     = p0;
            *reinterpret_cast<u16x8*>(&As[srow][sseg + 8]) = p1;
            const unsigned short* bp = WT + (size_t)(bn + srow) * K + kk + sseg;
            *reinterpret_cast<u16x8*>(&Bs[srow][sseg])     = *reinterpret_cast<const u16x8*>(bp);
            *reinterpret_cast<u16x8*>(&Bs[srow][sseg + 8]) = *reinterpret_cast<const u16x8*>(bp + 8);
        }
        __syncthreads();
#pragma unroll
        for (int ks = 0; ks < 2; ++ks) {
            bf16x8 a0 = *reinterpret_cast<const bf16x8*>(&As[wr * 32 + lo][ks * 32 + hi * 8]);
            bf16x8 a1 = *reinterpret_cast<const bf16x8*>(&As[wr * 32 + 16 + lo][ks * 32 + hi * 8]);
            bf16x8 b0 = *reinterpret_cast<const bf16x8*>(&Bs[wc * 32 + lo][ks * 32 + hi * 8]);
            bf16x8 b1 = *reinterpret_cast<const bf16x8*>(&Bs[wc * 32 + 16 + lo][ks * 32 + hi * 8]);
            acc[0][0] = __builtin_amdgcn_mfma_f32_16x16x32_bf16(a0, b0, acc[0][0], 0, 0, 0);
            acc[0][1] = __builtin_amdgcn_mfma_f32_16x16x32_bf16(a0, b1, acc[0][1], 0, 0, 0);
            acc[1][0] = __builtin_amdgcn_mfma_f32_16x16x32_bf16(a1, b0, acc[1][0], 0, 0, 0);
            acc[1][1] = __builtin_amdgcn_mfma_f32_16x16x32_bf16(a1, b1, acc[1][1], 0, 0, 0);
        }
        __syncthreads();
    }
    const float* bp = bias;
    float* Cp = C;
    int ldc = split ? split : N;
    int cb = bn;
    if (split && bn >= split) { bp = bias2; Cp = C2; ldc = N - split; cb = bn - split; }
#pragma unroll
    for (int i = 0; i < 2; ++i)
#pragma unroll
        for (int j = 0; j < 2; ++j) {
            int col = cb + wc * 32 + j * 16 + lo;
            float bv = bp[col];
#pragma unroll
            for (int r = 0; r < 4; ++r) {
                int row = bm + wr * 32 + i * 16 + hi * 4 + r;
                float v = acc[i][j][r] + bv;
                if (relu) v = fmaxf(v, 0.f);
                Cp[(size_t)row * ldc + col] = v;
            }
        }
}

// ---------------------------------------------------------------- attention
// Persistent-KV bf16 MFMA flash.  K == Q (kq_same), so Q fragments read from Ks.
// Grid: (b,h,half) = 256 blocks x 512 threads (8 waves). Stage ALL 512 keys of
// K and V^T once; each wave computes 2 query-groups (16 q each) with zero
// re-staging and no block barriers in the main loop (wave-local lgkmcnt only).
// strict==1: mask key>=query; query 0 -> uniform over all 512 keys (s=0).
__global__ __launch_bounds__(512) void attn_mfma(
    const float* __restrict__ Q, const float* __restrict__ V,
    float* __restrict__ Ctx, int strict)
{
    __shared__ __attribute__((aligned(16))) unsigned short Ks[512][40];     // 40 KB
    __shared__ __attribute__((aligned(16))) unsigned short VTc[8][32][72];  // 36 KB, per 64-key chunk
    __shared__ __attribute__((aligned(16))) unsigned short Ps[8][16][72];   // 18 KB, per wave (also f32 ctxbuf[16][36])

    int blk = blockIdx.x;
    int half = blk & 1;
    int h = (blk >> 1) & 7;
    int b = blk >> 4;
    int tid = threadIdx.x;
    int w = tid >> 6, lane = tid & 63;
    int lo = lane & 15, hi = lane >> 4;

    // ---- stage all of K (=Q) and V^T (once) ----
#pragma unroll
    for (int r = 0; r < 4; ++r) {
        int row = (tid >> 2) + r * 128;
        int d0 = (tid & 3) * 8;
        const float* kp = Q + ((size_t)b * CS + row) * CE + h * 32 + d0;
        float4 a = *reinterpret_cast<const float4*>(kp);
        float4 c = *reinterpret_cast<const float4*>(kp + 4);
        unsigned short* dst = &Ks[row][d0];
        dst[0]=f2bf(a.x); dst[1]=f2bf(a.y); dst[2]=f2bf(a.z); dst[3]=f2bf(a.w);
        dst[4]=f2bf(c.x); dst[5]=f2bf(c.y); dst[6]=f2bf(c.z); dst[7]=f2bf(c.w);
        const float* vp = V + ((size_t)b * CS + row) * CE + h * 32 + d0;
        float4 va = *reinterpret_cast<const float4*>(vp);
        float4 vc = *reinterpret_cast<const float4*>(vp + 4);
        int c8 = row >> 6, kc = row & 63;
        VTc[c8][d0+0][kc]=f2bf(va.x); VTc[c8][d0+1][kc]=f2bf(va.y);
        VTc[c8][d0+2][kc]=f2bf(va.z); VTc[c8][d0+3][kc]=f2bf(va.w);
        VTc[c8][d0+4][kc]=f2bf(vc.x); VTc[c8][d0+5][kc]=f2bf(vc.y);
        VTc[c8][d0+6][kc]=f2bf(vc.z); VTc[c8][d0+7][kc]=f2bf(vc.w);
    }
    __syncthreads();

    for (int it = 0; it < 2; ++it) {
        int gg = half * 16 + w + it * 8;     // global query group 0..31
        int qg0 = gg * 16;
        int qg = qg0 + lo;                   // this lane's query row
        bool uni = strict && (qg == 0);
        bf16x8 qfrag = *reinterpret_cast<const bf16x8*>(&Ks[qg0 + lo][hi * 8]);

        f32x4 ctx0 = {0.f,0.f,0.f,0.f}, ctx1 = {0.f,0.f,0.f,0.f};
        float m = -1e30f, l = 0.f;
        int nch = (strict && qg0 == 0) ? 8 : ((gg >> 2) + 1);

        for (int c = 0; c < nch; ++c) {
            f32x4 sacc[4];
#pragma unroll
            for (int kt = 0; kt < 4; ++kt) {
                bf16x8 kfrag = *reinterpret_cast<const bf16x8*>(&Ks[c * 64 + kt * 16 + lo][hi * 8]);
                f32x4 z = {0.f,0.f,0.f,0.f};
                sacc[kt] = __builtin_amdgcn_mfma_f32_16x16x32_bf16(kfrag, qfrag, z, 0, 0, 0);
            }
            float sv[16];
            float mt = -1e30f;
#pragma unroll
            for (int kt = 0; kt < 4; ++kt)
#pragma unroll
                for (int r = 0; r < 4; ++r) {
                    int kidx = c * 64 + kt * 16 + hi * 4 + r;
                    float s = sacc[kt][r] * SCALE;
                    bool valid = strict ? (kidx < qg) : (kidx <= qg);
                    s = valid ? s : -1e30f;
                    if (uni) s = 0.f;
                    sv[kt * 4 + r] = s;
                    mt = fmaxf(mt, s);
                }
            mt = fmaxf(mt, __shfl_xor(mt, 16));
            mt = fmaxf(mt, __shfl_xor(mt, 32));
            float mn = fmaxf(m, mt);
            float co = __expf(m - mn);
            float lt = 0.f;
#pragma unroll
            for (int i = 0; i < 16; ++i) {
                float p = __expf(sv[i] - mn);
                sv[i] = p;
                lt += p;
            }
            lt += __shfl_xor(lt, 16);
            lt += __shfl_xor(lt, 32);
            l = l * co + lt;
            m = mn;
#pragma unroll
            for (int r = 0; r < 4; ++r) { ctx0[r] *= co; ctx1[r] *= co; }
#pragma unroll
            for (int kt = 0; kt < 4; ++kt) {
                unsigned short* pd = &Ps[w][lo][kt * 16 + hi * 4];
                pd[0] = f2bf(sv[kt * 4 + 0]); pd[1] = f2bf(sv[kt * 4 + 1]);
                pd[2] = f2bf(sv[kt * 4 + 2]); pd[3] = f2bf(sv[kt * 4 + 3]);
            }
            // wave-local ordering: P writes (cross-lane) -> P reads
            asm volatile("s_waitcnt lgkmcnt(0)" ::: "memory");
            __builtin_amdgcn_sched_barrier(0);
#pragma unroll
            for (int kh = 0; kh < 2; ++kh) {
                bf16x8 pfrag = *reinterpret_cast<const bf16x8*>(&Ps[w][lo][kh * 32 + hi * 8]);
                bf16x8 v0 = *reinterpret_cast<const bf16x8*>(&VTc[c][lo][kh * 32 + hi * 8]);
                bf16x8 v1 = *reinterpret_cast<const bf16x8*>(&VTc[c][16 + lo][kh * 32 + hi * 8]);
                ctx0 = __builtin_amdgcn_mfma_f32_16x16x32_bf16(v0, pfrag, ctx0, 0, 0, 0);
                ctx1 = __builtin_amdgcn_mfma_f32_16x16x32_bf16(v1, pfrag, ctx1, 0, 0, 0);
            }
        }

        // ---- normalize + writeout via per-wave LDS transpose ----
        float inv = 1.f / l;
        float* cb = reinterpret_cast<float*>(&Ps[w][0][0]);   // [16 q][36 d]
#pragma unroll
        for (int r = 0; r < 4; ++r) {
            cb[lo * 36 + (hi * 4 + r)]      = ctx0[r] * inv;
            cb[lo * 36 + (16 + hi * 4 + r)] = ctx1[r] * inv;
        }
        asm volatile("s_waitcnt lgkmcnt(0)" ::: "memory");
        __builtin_amdgcn_sched_barrier(0);
        {
            int qloc = lane >> 2, d0 = (lane & 3) * 8;
            const float* src = cb + qloc * 36 + d0;
            float4 o0 = *reinterpret_cast<const float4*>(src);
            float4 o1 = *reinterpret_cast<const float4*>(src + 4);
            int i = qg0 + qloc;
            float* op = Ctx + ((size_t)b * CS + i) * CE + h * 32 + d0;
            *reinterpret_cast<float4*>(op)     = o0;
            *reinterpret_cast<float4*>(op + 4) = o1;
        }
        asm volatile("s_waitcnt lgkmcnt(0)" ::: "memory");   // cb reads done before next it's P writes
        __builtin_amdgcn_sched_barrier(0);
    }
}

// ---------------------------------------------------------------- router gate mask
// Wave per token (8 waves/block): logits = q_in @ Wg; top-4 -> 8-bit head mask.
__global__ __launch_bounds__(512) void gate_mask(
    const float* __restrict__ qin, const float* __restrict__ Wg,
    unsigned char* __restrict__ mb)
{
    int w = threadIdx.x >> 6, lane = threadIdx.x & 63;
    int t = blockIdx.x * 8 + w;
    const float* q = qin + (size_t)t * CE;
    float p[CNDYN] = {};
#pragma unroll
    for (int r = 0; r < 4; ++r) {
        int e = lane + r * 64;
        float qe = q[e];
        const float* wg = &Wg[(size_t)e * CNDYN];
#pragma unroll
        for (int j = 0; j < CNDYN; ++j) p[j] += qe * wg[j];
    }
#pragma unroll
    for (int o = 32; o > 0; o >>= 1)
#pragma unroll
        for (int j = 0; j < CNDYN; ++j) p[j] += __shfl_down(p[j], o);
    if (lane == 0) {
        int mask = 3;
        for (int j = 0; j < CNDYN; ++j) {
            int rank = 0;
            for (int k = 0; k < CNDYN; ++k)
                if (p[k] > p[j] || (p[k] == p[j] && k < j)) rank++;
            if (rank < 4) mask |= 1 << (2 + j);
        }
        mb[t] = (unsigned char)mask;
    }
}

// ---------------------------------------------------------------- residual+LN
__global__ __launch_bounds__(256) void add_ln(
    const float* __restrict__ A, const float* __restrict__ Bv,
    const float* __restrict__ g, const float* __restrict__ bb,
    float* __restrict__ O)
{
    int w = threadIdx.x >> 6, lane = threadIdx.x & 63;
    int t = blockIdx.x * 4 + w;
    size_t base = (size_t)t * CE + lane * 4;
    float4 a = *reinterpret_cast<const float4*>(A + base);
    float4 b = *reinterpret_cast<const float4*>(Bv + base);
    float4 v = {a.x + b.x, a.y + b.y, a.z + b.z, a.w + b.w};
    float s = v.x + v.y + v.z + v.w;
#pragma unroll
    for (int o = 32; o > 0; o >>= 1) s += __shfl_xor(s, o);
    float mean = s * (1.f / CE);
    float4 d = {v.x - mean, v.y - mean, v.z - mean, v.w - mean};
    float s2 = d.x * d.x + d.y * d.y + d.z * d.z + d.w * d.w;
#pragma unroll
    for (int o = 32; o > 0; o >>= 1) s2 += __shfl_xor(s2, o);
    float rstd = rsqrtf(s2 * (1.f / CE) + 1e-5f);
    float4 gg = *reinterpret_cast<const float4*>(g + lane * 4);
    float4 bv4 = *reinterpret_cast<const float4*>(bb + lane * 4);
    float4 o4 = {d.x * rstd * gg.x + bv4.x, d.y * rstd * gg.y + bv4.y,
                 d.z * rstd * gg.z + bv4.z, d.w * rstd * gg.w + bv4.w};
    *reinterpret_cast<float4*>(O + base) = o4;
}

// ---------------------------------------------------------------- concat
__global__ __launch_bounds__(256) void concat_kernel(
    const float* __restrict__ x, const float* __restrict__ qe,
    float* __restrict__ cat)
{
    int t = blockIdx.x, e = threadIdx.x;
    cat[(size_t)t * 512 + e]       = x[(size_t)t * CE + e];
    cat[(size_t)t * 512 + 256 + e] = qe[(size_t)t * CE + e];
}

// ---------------------------------------------------------------- final dot + sigmoid
__global__ __launch_bounds__(64) void final_kernel(
    const float* __restrict__ H2, const float* __restrict__ W3,
    const float* __restrict__ b3, float* __restrict__ out)
{
    int t = blockIdx.x, lane = threadIdx.x;
    const float* h = H2 + (size_t)t * CE;
    float s = 0.f;
#pragma unroll
    for (int r = 0; r < 4; ++r) {
        int e = lane + r * 64;
        s += h[e] * W3[e];
    }
#pragma unroll
    for (int o = 32; o > 0; o >>= 1) s += __shfl_down(s, o);
    if (lane == 0) {
        float v = 1.f / (1.f + __expf(-(s + b3[0])));
        int b = t >> 9, si = t & 511;
        if (si > 0) out[(size_t)b * (CS - 1) + si - 1] = v;
    }
}

// ---------------------------------------------------------------- driver
extern "C" void kernel_launch(void* const* d_in, const int* in_sizes, int n_in,
                              void* d_out, int out_size, void* d_ws, size_t ws_size,
                              hipStream_t stream)
{
    const int* skills    = (const int*)d_in[0];
    const int* responses = (const int*)d_in[1];
    const int* questions = (const int*)d_in[2];
    const float* q_embed       = (const float*)d_in[4];
    const float* qa_embed      = (const float*)d_in[5];
    const float* q_embed_diff  = (const float*)d_in[6];
    const float* qa_embed_diff = (const float*)d_in[7];
    const float* difficult     = (const float*)d_in[8];
    const float* Wq = (const float*)d_in[9];  const float* bq = (const float*)d_in[10];
    const float* Wv = (const float*)d_in[11]; const float* bv = (const float*)d_in[12];
    const float* Wo = (const float*)d_in[13]; const float* bo = (const float*)d_in[14];
    const float* Wg = (const float*)d_in[15];
    const float* ln1g = (const float*)d_in[16]; const float* ln1b = (const float*)d_in[17];
    const float* ln2g = (const float*)d_in[18]; const float* ln2b = (const float*)d_in[19];
    const float* fW1 = (const float*)d_in[20]; const float* fb1 = (const float*)d_in[21];
    const float* fW2 = (const float*)d_in[22]; const float* fb2 = (const float*)d_in[23];
    const float* oW1 = (const float*)d_in[24]; const float* ob1 = (const float*)d_in[25];
    const float* oW2 = (const float*)d_in[26]; const float* ob2 = (const float*)d_in[27];
    const float* oW3 = (const float*)d_in[28]; const float* ob3 = (const float*)d_in[29];
    float* out = (float*)d_out;

    char* ws = (char*)d_ws;
    const size_t R = (size_t)CT * CE * sizeof(float);   // 8 MB per region
    float* q_emb = (float*)(ws + 0 * R);
    float* xb    = (float*)(ws + 1 * R);
    float* yb    = (float*)(ws + 2 * R);
    float* S0    = (float*)(ws + 3 * R);   // S0..S1: 16MB cat buffer
    float* S1    = (float*)(ws + 4 * R);
    float* S2    = (float*)(ws + 5 * R);   // S2..S3: 16MB H1 buffer
    unsigned short* qvT = (unsigned short*)(ws + 7 * R);  // [12][512][256]
    unsigned short* woT = qvT + (size_t)12 * 131072;      // [12][256][256]
    unsigned short* w1T = woT + (size_t)12 * 65536;
    unsigned short* w2T = w1T + (size_t)12 * 65536;
    unsigned short* o1T = w2T + (size_t)12 * 65536;       // [512][512]
    unsigned short* o2T = o1T + (size_t)512 * 512;        // [256][512]
    unsigned char* maskbuf = (unsigned char*)(o2T + (size_t)256 * 512);
    (void)in_sizes; (void)n_in; (void)out_size; (void)ws_size;

    // weight conversion (every call; graph-safe)
    prep_w_layers<<<dim3(4, 4, 60), 256, 0, stream>>>(Wq, Wv, Wo, fW1, fW2, qvT, woT, w1T, w2T);
    prep_w_one<<<dim3(8, 8), 256, 0, stream>>>(oW1, o1T, 512, 512);
    prep_w_one<<<dim3(4, 8), 256, 0, stream>>>(oW2, o2T, 512, 256);

    embed_kernel<<<CT, 256, 0, stream>>>(skills, responses, questions,
        q_embed, qa_embed, q_embed_diff, qa_embed_diff, difficult, q_emb, yb, xb);

    auto layer = [&](int li, const float* qin, const float* vin, float* outc, int strict) {
        if (qin == vin) {   // fused Q+V projection (N=512, split at 256)
            gemm_mfma<<<dim3(8, 128), 256, 0, stream>>>(qin, qvT + (size_t)li * 131072,
                bq + (size_t)li * CE, S0, bv + (size_t)li * CE, S1, nullptr,
                CT, 512, CE, 0, 256);
        } else {
            gemm_mfma<<<dim3(4, 128), 256, 0, stream>>>(qin, qvT + (size_t)li * 131072,
                bq + (size_t)li * CE, S0, nullptr, nullptr, nullptr, CT, CE, CE, 0, 0);
            gemm_mfma<<<dim3(4, 128), 256, 0, stream>>>(vin, qvT + (size_t)li * 131072 + 65536,
                bv + (size_t)li * CE, S1, nullptr, nullptr, nullptr, CT, CE, CE, 0, 0);
        }
        gate_mask<<<CT / 8, 512, 0, stream>>>(qin, Wg + (size_t)li * CE * CNDYN, maskbuf);
        attn_mfma<<<CB * CH * 2, 512, 0, stream>>>(S0, S1, S2, strict);
        gemm_mfma<<<dim3(4, 128), 256, 0, stream>>>(S2, woT + (size_t)li * 65536,
            bo + (size_t)li * CE, S0, nullptr, nullptr, maskbuf, CT, CE, CE, 0, 0);
        add_ln<<<CT / 4, 256, 0, stream>>>(qin, S0, ln1g + (size_t)li * CE, ln1b + (size_t)li * CE, S1);
        gemm_mfma<<<dim3(4, 128), 256, 0, stream>>>(S1, w1T + (size_t)li * 65536,
            fb1 + (size_t)li * CE, S2, nullptr, nullptr, nullptr, CT, CE, CE, 1, 0);
        gemm_mfma<<<dim3(4, 128), 256, 0, stream>>>(S2, w2T + (size_t)li * 65536,
            fb2 + (size_t)li * CE, S0, nullptr, nullptr, nullptr, CT, CE, CE, 0, 0);
        add_ln<<<CT / 4, 256, 0, stream>>>(S1, S0, ln2g + (size_t)li * CE, ln2b + (size_t)li * CE, outc);
    };

    for (int i = 0; i < 4; ++i) layer(i, yb, yb, yb, 0);
    int li = 4;
    for (int r = 0; r < 4; ++r) {
        layer(li, xb, xb, xb, 0); li++;
        layer(li, xb, yb, xb, 1); li++;   // q=x, k=x, v=y, strict mask
    }

    // output MLP
    concat_kernel<<<CT, 256, 0, stream>>>(xb, q_emb, S0);
    gemm_mfma<<<dim3(8, 128), 256, 0, stream>>>(S0, o1T, ob1, S2, nullptr, nullptr, nullptr, CT, 512, 512, 1, 0);
    gemm_mfma<<<dim3(4, 128), 256, 0, stream>>>(S2, o2T, ob2, xb, nullptr, nullptr, nullptr, CT, 256, 512, 1, 0);
    final_kernel<<<CT, 64, 0, stream>>>(xb, oW3, ob3, out);
}